// Round 6
// baseline (428.260 us; speedup 1.0000x reference)
//
#include <hip/hip_runtime.h>
#include <cstdint>
#include <cstddef>

typedef unsigned short u16;
typedef __attribute__((ext_vector_type(8))) short s16x8;
typedef __attribute__((ext_vector_type(4))) float f32x4;

#define DEV __device__ __forceinline__

DEV float bf2f(short u){
  union { unsigned int i; float f; } v;
  v.i = ((unsigned int)(u16)u) << 16;
  return v.f;
}
DEV short f2bf(float f){
  union { float f; unsigned int i; } v; v.f = f;
  unsigned int u = v.i;
  u += 0x7fffu + ((u >> 16) & 1u);   // RNE
  return (short)(u >> 16);
}
DEV s16x8 s16x8_zero(){
  s16x8 z;
#pragma unroll
  for(int j=0;j<8;j++) z[j]=0;
  return z;
}
DEV f32x4 f32x4_zero(){
  f32x4 z;
#pragma unroll
  for(int j=0;j<4;j++) z[j]=0.f;
  return z;
}
DEV f32x4 mfma16(s16x8 a, s16x8 b, f32x4 c){
  return __builtin_amdgcn_mfma_f32_16x16x32_bf16(a, b, c, 0, 0, 0);
}
DEV void bar_lds(){
  asm volatile("s_waitcnt lgkmcnt(0)");
  __builtin_amdgcn_s_barrier();
}
// async global -> LDS, 16 B per lane; dst is wave-uniform base (+lane*16 implicit)
DEV void gload16(const u16* g, u16* l){
  __builtin_amdgcn_global_load_lds(
      (const __attribute__((address_space(1))) unsigned int*)g,
      (__attribute__((address_space(3))) unsigned int*)l, 16, 0, 0);
}

// ---------------- problem constants ----------------
// B=4, Cin=512 (concat), H=W=64, P=9 taps, Cout=256, M = B*H*W = 16384
// Padded spatial layouts: [4][66][66][C], zero borders (memset'd).
static constexpr size_t OFF_ACC_B   = 0;                         // float[16384*32]
static constexpr size_t STATS_B     = 2097152;                   // float[1024]
static constexpr size_t OUT1_ACC_B  = 2101248;                   // float[16384*256]
static constexpr size_t OUT2_ACC_B  = 18878464;                  // float[16384*256]
static constexpr size_t XN_PAD_B    = 35655680;                  // u16[4*66*66*512]
static constexpr size_t OUT1N_PAD_B = 53497856;                  // u16[4*66*66*256]
static constexpr size_t ZERO_BYTES  = 62418944;
static constexpr size_t S_B         = 62418944;                  // u16[16384*4608]
static constexpr size_t WOFFT_B     = 213708800;                 // u16[32*4608]
static constexpr size_t WDCNT_B     = 214003712;                 // u16[256*4608]
static constexpr size_t W2T_B       = 216363008;                 // u16[256*2304]
static constexpr size_t POFS_B      = 217542656;                 // int[16384*9*4]
static constexpr size_t PWGT_B      = 219901952;                 // float[16384*9*4]
// total ~212 MB

// ---------------- NCHW fp32 (concat) -> padded NHWC bf16 ----------------
__global__ void k_x_to_nhwc(const float* __restrict__ v, const float* __restrict__ vi,
                            u16* __restrict__ xn){
  __shared__ float tile[64][65];
  const int b = blockIdx.z, c0 = blockIdx.y*64, hw0 = blockIdx.x*64;
  const int h = hw0 >> 6;                  // one image row per block
  const float* src = (c0 < 256) ? (v  + ((size_t)b*256 + c0)      *4096)
                                : (vi + ((size_t)b*256 + (c0-256))*4096);
  const int t = threadIdx.x;
#pragma unroll
  for(int k=0;k<16;k++){
    int idx = t + k*256;
    int cl = idx >> 6, wl = idx & 63;
    tile[cl][wl] = src[(size_t)cl*4096 + hw0 + wl];
  }
  __syncthreads();
#pragma unroll
  for(int k=0;k<16;k++){
    int idx = t + k*256;
    int wl = idx >> 6, cl = idx & 63;
    xn[((size_t)(b*66 + h+1)*66 + wl+1)*512 + c0 + cl] = (u16)f2bf(tile[cl][wl]);
  }
}

// ---------------- weight repacks: OIHW fp32 -> [N][K] bf16, K = tap*C + c ----------------
__global__ void k_prep_woff(const float* __restrict__ w, u16* __restrict__ wt){
  int idx = blockIdx.x*256 + threadIdx.x;
  if(idx >= 32*4608) return;
  int n = idx / 4608, k = idx % 4608;
  int t = k >> 9, c = k & 511;
  float val = (n < 27) ? w[(size_t)(n*512 + c)*9 + t] : 0.f;
  wt[idx] = (u16)f2bf(val);
}
__global__ void k_prep_wdcn(const float* __restrict__ w, u16* __restrict__ wt){
  int idx = blockIdx.x*256 + threadIdx.x;
  if(idx >= 256*4608) return;
  int n = idx / 4608, k = idx % 4608;
  int t = k >> 9, c = k & 511;
  wt[idx] = (u16)f2bf(w[(size_t)(n*512 + c)*9 + t]);
}
__global__ void k_prep_w2(const float* __restrict__ w, u16* __restrict__ wt){
  int idx = blockIdx.x*256 + threadIdx.x;
  if(idx >= 256*2304) return;
  int n = idx / 2304, k = idx % 2304;
  int t = k >> 8, c = k & 255;
  wt[idx] = (u16)f2bf(w[(size_t)(n*256 + c)*9 + t]);
}

// ---------------- offset conv: 512ch -> 27(pad 32), implicit GEMM (padded input) --------
__global__ __launch_bounds__(256, 2) void k_conv_off(
    const u16* __restrict__ xn, const u16* __restrict__ wt, float* __restrict__ offa){
  __shared__ short A_lds[4][128][8];
  __shared__ short B_lds[4][32][8];
  const int tid = threadIdx.x;
  const int lane = tid & 63, wid = tid >> 6;
  const int quad = lane >> 4, ln = lane & 15;
  const int m0 = blockIdx.x * 128;
  const int b = m0 >> 12;
  const int h0 = (m0 & 4095) >> 6;
  const int ks = blockIdx.y;
  const int ts0 = (ks == 3) ? 6 : ks*2;
  const int ntap = (ks == 3) ? 3 : 2;
  const int m_base = wid * 32;
  const int r = tid >> 1, sp = (tid & 1) * 2;
  const int h_r = h0 + (r >> 6), w_r = r & 63;
  const s16x8* Ap = (const s16x8*)A_lds;
  const s16x8* Bp = (const s16x8*)B_lds;
  f32x4 acc[2][2];
#pragma unroll
  for(int mf=0;mf<2;mf++)
#pragma unroll
    for(int nf=0;nf<2;nf++) acc[mf][nf] = f32x4_zero();

  auto load_it = [&](int it, s16x8& v0, s16x8& v1, s16x8& bv){
    const int tp = ts0 + (it >> 4);
    const int cA = (it & 15)*32;
    const int ty = tp/3, tx = tp - ty*3;
    const int y = h_r + ty, x = w_r + tx;   // padded coords (h-1+ty)+1
    const u16* src = xn + ((size_t)(b*66 + y)*66 + x)*512 + cA + sp*8;
    v0 = *(const s16x8*)(src);
    v1 = *(const s16x8*)(src + 8);
    if(tid < 128){
      const int n = tid & 31, s2 = tid >> 5;
      bv = *(const s16x8*)(wt + (size_t)n*4608 + tp*512 + cA + s2*8);
    }
  };

  const int NIT = ntap * 16;
  s16x8 v0a, v1a, bva, v0b, v1b, bvb;
  bva = s16x8_zero(); bvb = s16x8_zero();
  load_it(0, v0a, v1a, bva);
  load_it(1, v0b, v1b, bvb);
  for(int it = 0; it < NIT; it += 2){
    bar_lds();
    *(s16x8*)(&A_lds[sp][r][0])   = v0a;
    *(s16x8*)(&A_lds[sp+1][r][0]) = v1a;
    if(tid < 128){
      const int n = tid & 31, s2 = tid >> 5;
      *(s16x8*)(&B_lds[s2][n][0]) = bva;
    }
    if(it + 2 < NIT) load_it(it + 2, v0a, v1a, bva);
    bar_lds();
    {
      s16x8 a0 = Ap[quad*128 + m_base + ln];
      s16x8 a1 = Ap[quad*128 + m_base + 16 + ln];
      s16x8 b0 = Bp[quad*32 + ln];
      s16x8 b1 = Bp[quad*32 + 16 + ln];
      acc[0][0] = mfma16(a0, b0, acc[0][0]);
      acc[0][1] = mfma16(a0, b1, acc[0][1]);
      acc[1][0] = mfma16(a1, b0, acc[1][0]);
      acc[1][1] = mfma16(a1, b1, acc[1][1]);
    }
    bar_lds();
    *(s16x8*)(&A_lds[sp][r][0])   = v0b;
    *(s16x8*)(&A_lds[sp+1][r][0]) = v1b;
    if(tid < 128){
      const int n = tid & 31, s2 = tid >> 5;
      *(s16x8*)(&B_lds[s2][n][0]) = bvb;
    }
    if(it + 3 < NIT) load_it(it + 3, v0b, v1b, bvb);
    bar_lds();
    {
      s16x8 a0 = Ap[quad*128 + m_base + ln];
      s16x8 a1 = Ap[quad*128 + m_base + 16 + ln];
      s16x8 b0 = Bp[quad*32 + ln];
      s16x8 b1 = Bp[quad*32 + 16 + ln];
      acc[0][0] = mfma16(a0, b0, acc[0][0]);
      acc[0][1] = mfma16(a0, b1, acc[0][1]);
      acc[1][0] = mfma16(a1, b0, acc[1][0]);
      acc[1][1] = mfma16(a1, b1, acc[1][1]);
    }
  }
#pragma unroll
  for(int mf=0;mf<2;mf++)
#pragma unroll
    for(int nf=0;nf<2;nf++){
      const int col = nf*16 + ln;
#pragma unroll
      for(int i=0;i<4;i++){
        const int row = m_base + mf*16 + quad*4 + i;
        unsafeAtomicAdd(offa + (size_t)(m0+row)*32 + col, acc[mf][nf][i]);
      }
    }
}

// ---------------- precompute bilinear offsets/weights -> global ----------------
__global__ void k_prep_off2(const float* __restrict__ offa, const float* __restrict__ boff,
                            int* __restrict__ pofs, float* __restrict__ pwgt){
  int id = blockIdx.x*256 + threadIdx.x;
  if(id >= 16384*9) return;
  int m = id / 9, tp = id - m*9;
  int b = m >> 12, h = (m >> 6) & 63, w = m & 63;
  const float* orow = offa + (size_t)m*32;
  float dy = orow[2*tp]   + boff[2*tp];
  float dx = orow[2*tp+1] + boff[2*tp+1];
  float mz = orow[18+tp]  + boff[18+tp];
  float mk = 1.f / (1.f + expf(-mz));
  float ypos = (float)(h - 1 + tp/3) + dy;
  float xpos = (float)(w - 1 + tp%3) + dx;
  float y0f = floorf(ypos), x0f = floorf(xpos);
  float ly = ypos - y0f, lx = xpos - x0f;
  int y0 = (int)y0f, x0 = (int)x0f;
#pragma unroll
  for(int k=0;k<4;k++){
    int ddy = k >> 1, ddx = k & 1;
    int yi = y0 + ddy, xi = x0 + ddx;
    // padded buffer: clamp into [-1,64] -> index [0,65]; border rows are zeros,
    // so any OOB neighbor contributes 0 regardless of weight (matches reference).
    int yc = yi < -1 ? -1 : (yi > 64 ? 64 : yi);
    int xc = xi < -1 ? -1 : (xi > 64 ? 64 : xi);
    float wk = (ddy ? ly : 1.f-ly) * (ddx ? lx : 1.f-lx) * mk;
    pofs[id*4+k] = ((b*66 + yc+1)*66 + xc+1) << 9;   // *512 channels
    pwgt[id*4+k] = wk;
  }
}

// ---------------- sample+blend: materialize im2col S[16384][4608] bf16 ----------------
// grid (4096, 9): wave = one (pixel,tap); lane = one 8-ch octet. No barriers, max TLP.
__global__ __launch_bounds__(256) void k_sample(
    const u16* __restrict__ xn, const int* __restrict__ pofs,
    const float* __restrict__ pwgt, u16* __restrict__ S){
  const int wid = threadIdx.x >> 6, lane = threadIdx.x & 63;
  const int m = blockIdx.x*4 + wid;
  const int tp = blockIdx.y;
  const int id4 = (m*9 + tp)*4;
  const int4   of = *(const int4*)  (pofs + id4);
  const float4 wg = *(const float4*)(pwgt + id4);
  const int c0 = lane*8;
  s16x8 g0 = *(const s16x8*)(xn + of.x + c0);
  s16x8 g1 = *(const s16x8*)(xn + of.y + c0);
  s16x8 g2 = *(const s16x8*)(xn + of.z + c0);
  s16x8 g3 = *(const s16x8*)(xn + of.w + c0);
  s16x8 pk;
#pragma unroll
  for(int j=0;j<8;j++){
    float f = wg.x * bf2f(g0[j]);
    f = fmaf(wg.y, bf2f(g1[j]), f);
    f = fmaf(wg.z, bf2f(g2[j]), f);
    f = fmaf(wg.w, bf2f(g3[j]), f);
    pk[j] = f2bf(f);
  }
  *(s16x8*)(S + (size_t)m*4608 + tp*512 + c0) = pk;
}

// ---------------- GEMM1: out1 = S[16384][4608] x WdcnT[256][4608]^T ----------------
// m97-style: 64x128 tile, BK=64, single-buffer LDS (24KB), full-drain barriers,
// split-K x2 -> grid (256,2,2) = 1024 blocks = 4/CU.
__global__ __launch_bounds__(256, 4) void k_gemm1(
    const u16* __restrict__ S, const u16* __restrict__ wt, float* __restrict__ outa){
  __shared__ short A_lds[8][64][8];     // 8 KB  [k-slice][m-row][8]
  __shared__ short B_lds[8][128][8];    // 16 KB [k-slice][n-row][8]
  const int tid = threadIdx.x;
  const int lane = tid & 63, wid = tid >> 6;
  const int quad = lane >> 4, ln = lane & 15;
  const int wm = wid >> 1, wn = wid & 1;       // 2x2 wave grid: 32m x 64n each
  const int m0 = blockIdx.x * 64;
  const int n0 = blockIdx.y * 128;
  const int kbase = blockIdx.z * 2304;
  const u16* Arow = S + (size_t)(m0 + lane)*4608;
  f32x4 acc[2][4];
#pragma unroll
  for(int mf=0;mf<2;mf++)
#pragma unroll
    for(int nf=0;nf<4;nf++) acc[mf][nf] = f32x4_zero();

  for(int t = 0; t < 36; ++t){
    const int k0 = kbase + t*64;
    // stage A: 8 x 1KB (2 per wave)
#pragma unroll
    for(int i=0;i<2;i++){
      const int g = wid*2 + i;
      gload16(Arow + k0 + g*8, (u16*)&A_lds[g][0][0]);
    }
    // stage B: 16 x 1KB (4 per wave)
#pragma unroll
    for(int i=0;i<4;i++){
      const int g2 = wid*4 + i;
      gload16(wt + (size_t)(n0 + (g2&1)*64 + lane)*4608 + k0 + (g2>>1)*8,
              (u16*)&B_lds[g2>>1][(g2&1)*64][0]);
    }
    __syncthreads();   // drains gload_lds (vmcnt) + makes LDS visible
#pragma unroll
    for(int kk=0;kk<2;kk++){
      s16x8 af[2], bf[4];
#pragma unroll
      for(int mf=0;mf<2;mf++)
        af[mf] = *(const s16x8*)&A_lds[kk*4+quad][wm*32 + mf*16 + ln][0];
#pragma unroll
      for(int nf=0;nf<4;nf++)
        bf[nf] = *(const s16x8*)&B_lds[kk*4+quad][wn*64 + nf*16 + ln][0];
#pragma unroll
      for(int mf=0;mf<2;mf++)
#pragma unroll
        for(int nf=0;nf<4;nf++)
          acc[mf][nf] = mfma16(af[mf], bf[nf], acc[mf][nf]);
    }
    __syncthreads();   // protect LDS from next stage
  }
#pragma unroll
  for(int mf=0;mf<2;mf++)
#pragma unroll
    for(int nf=0;nf<4;nf++){
      const int col = n0 + wn*64 + nf*16 + ln;
#pragma unroll
      for(int i=0;i<4;i++){
        const int row = m0 + wm*32 + mf*16 + quad*4 + i;
        unsafeAtomicAdd(outa + (size_t)row*256 + col, acc[mf][nf][i]);
      }
    }
}

// ---------------- GEMM2: out2 = im2col(out1n_pad)[16384][2304] x W2T[256][2304]^T ------
// same structure; A staged from padded activations (no bounds checks).
__global__ __launch_bounds__(256, 4) void k_gemm2(
    const u16* __restrict__ a_pad, const u16* __restrict__ wt, float* __restrict__ outa){
  __shared__ short A_lds[8][64][8];     // 8 KB
  __shared__ short B_lds[8][128][8];    // 16 KB
  const int tid = threadIdx.x;
  const int lane = tid & 63, wid = tid >> 6;
  const int quad = lane >> 4, ln = lane & 15;
  const int wm = wid >> 1, wn = wid & 1;
  const int m0 = blockIdx.x * 64;       // one image row: b,h fixed, w = lane
  const int n0 = blockIdx.y * 128;
  const int kbase = blockIdx.z * 1152;
  const int b = m0 >> 12;
  const int h = (m0 & 4095) >> 6;
  f32x4 acc[2][4];
#pragma unroll
  for(int mf=0;mf<2;mf++)
#pragma unroll
    for(int nf=0;nf<4;nf++) acc[mf][nf] = f32x4_zero();

  for(int t = 0; t < 18; ++t){
    const int k0 = kbase + t*64;
    const int tp = k0 >> 8, cit = k0 & 255;
    const int ty = tp/3, tx = tp - ty*3;
    const u16* Arow = a_pad + ((size_t)(b*66 + h + ty)*66 + lane + tx)*256 + cit;
#pragma unroll
    for(int i=0;i<2;i++){
      const int g = wid*2 + i;
      gload16(Arow + g*8, (u16*)&A_lds[g][0][0]);
    }
#pragma unroll
    for(int i=0;i<4;i++){
      const int g2 = wid*4 + i;
      gload16(wt + (size_t)(n0 + (g2&1)*64 + lane)*2304 + k0 + (g2>>1)*8,
              (u16*)&B_lds[g2>>1][(g2&1)*64][0]);
    }
    __syncthreads();
#pragma unroll
    for(int kk=0;kk<2;kk++){
      s16x8 af[2], bf[4];
#pragma unroll
      for(int mf=0;mf<2;mf++)
        af[mf] = *(const s16x8*)&A_lds[kk*4+quad][wm*32 + mf*16 + ln][0];
#pragma unroll
      for(int nf=0;nf<4;nf++)
        bf[nf] = *(const s16x8*)&B_lds[kk*4+quad][wn*64 + nf*16 + ln][0];
#pragma unroll
      for(int mf=0;mf<2;mf++)
#pragma unroll
        for(int nf=0;nf<4;nf++)
          acc[mf][nf] = mfma16(af[mf], bf[nf], acc[mf][nf]);
    }
    __syncthreads();
  }
#pragma unroll
  for(int mf=0;mf<2;mf++)
#pragma unroll
    for(int nf=0;nf<4;nf++){
      const int col = n0 + wn*64 + nf*16 + ln;
#pragma unroll
      for(int i=0;i<4;i++){
        const int row = m0 + wm*32 + mf*16 + quad*4 + i;
        unsafeAtomicAdd(outa + (size_t)row*256 + col, acc[mf][nf][i]);
      }
    }
}

// ---------------- BN stats: per-channel sum/sumsq over M=16384 ----------------
__global__ void k_stats(const float* __restrict__ acc, float* __restrict__ sum,
                        float* __restrict__ sq){
  const int m0 = blockIdx.x*64;
  const int c = threadIdx.x;
  float s = 0.f, q = 0.f;
  for(int i=0;i<64;i++){
    float v = acc[(size_t)(m0+i)*256 + c];
    s += v; q += v*v;
  }
  unsafeAtomicAdd(sum + c, s);
  unsafeAtomicAdd(sq + c, q);
}

// ---------------- BN1 + ReLU -> padded bf16 NHWC ----------------
__global__ void k_bn1(const float* __restrict__ acc, const float* __restrict__ sum,
                      const float* __restrict__ sq, const float* __restrict__ g,
                      const float* __restrict__ bt, u16* __restrict__ o){
  __shared__ float sc[256], sh[256];
  const int t = threadIdx.x;
  {
    float mean = sum[t] * (1.f/16384.f);
    float var  = sq[t] * (1.f/16384.f) - mean*mean;
    float rstd = rsqrtf(var + 1e-5f);
    float s = g[t] * rstd;
    sc[t] = s; sh[t] = bt[t] - mean*s;
  }
  __syncthreads();
  const int c4 = (t & 63) * 4;
  const float s0 = sc[c4], s1 = sc[c4+1], s2 = sc[c4+2], s3 = sc[c4+3];
  const float h0 = sh[c4], h1 = sh[c4+1], h2 = sh[c4+2], h3 = sh[c4+3];
#pragma unroll
  for(int k=0;k<4;k++){
    int m = blockIdx.x*16 + k*4 + (t>>6);
    int b = m >> 12, hh = (m >> 6) & 63, ww = m & 63;
    const float4 v = *(const float4*)(acc + (size_t)m*256 + c4);
    unsigned int lo = (unsigned int)(u16)f2bf(fmaxf(0.f, v.x*s0 + h0))
                    | ((unsigned int)(u16)f2bf(fmaxf(0.f, v.y*s1 + h1)) << 16);
    unsigned int hi = (unsigned int)(u16)f2bf(fmaxf(0.f, v.z*s2 + h2))
                    | ((unsigned int)(u16)f2bf(fmaxf(0.f, v.w*s3 + h3)) << 16);
    uint2 pr; pr.x = lo; pr.y = hi;
    *(uint2*)(o + ((size_t)(b*66 + hh+1)*66 + ww+1)*256 + c4) = pr;
  }
}

// ---------------- BN2 + ReLU + NHWC->NCHW fp32 output ----------------
__global__ void k_bn2_out(const float* __restrict__ acc, const float* __restrict__ sum,
                          const float* __restrict__ sq, const float* __restrict__ g,
                          const float* __restrict__ bt, float* __restrict__ out){
  __shared__ float tile[64][65];
  __shared__ float sc[64], sh[64];
  const int t = threadIdx.x;
  const int b = blockIdx.z, c0 = blockIdx.y*64, hw0 = blockIdx.x*64;
  if(t < 64){
    int c = c0 + t;
    float mean = sum[c] * (1.f/16384.f);
    float var  = sq[c] * (1.f/16384.f) - mean*mean;
    float rstd = rsqrtf(var + 1e-5f);
    float s = g[c] * rstd;
    sc[t] = s; sh[t] = bt[c] - mean*s;
  }
  __syncthreads();
#pragma unroll
  for(int k=0;k<16;k++){
    int idx = t + k*256;
    int wl = idx >> 6, cl = idx & 63;
    float v = acc[(size_t)((b<<12) + hw0 + wl)*256 + c0 + cl];
    tile[wl][cl] = fmaxf(0.f, v*sc[cl] + sh[cl]);
  }
  __syncthreads();
#pragma unroll
  for(int k=0;k<16;k++){
    int idx = t + k*256;
    int cl = idx >> 6, wl = idx & 63;
    out[(size_t)(b*256 + c0 + cl)*4096 + hw0 + wl] = tile[wl][cl];
  }
}

extern "C" void kernel_launch(void* const* d_in, const int* in_sizes, int n_in,
                              void* d_out, int out_size, void* d_ws, size_t ws_size,
                              hipStream_t stream){
  const float* in_v  = (const float*)d_in[0];
  const float* in_i  = (const float*)d_in[1];
  const float* w_off = (const float*)d_in[2];
  const float* b_off = (const float*)d_in[3];
  const float* w_dcn = (const float*)d_in[4];
  const float* g1    = (const float*)d_in[5];
  const float* bt1   = (const float*)d_in[6];
  const float* w2    = (const float*)d_in[7];
  const float* g2    = (const float*)d_in[8];
  const float* bt2   = (const float*)d_in[9];
  float* out = (float*)d_out;
  char* ws = (char*)d_ws;

  float* off_acc   = (float*)(ws + OFF_ACC_B);
  float* stats     = (float*)(ws + STATS_B);
  float* out1_acc  = (float*)(ws + OUT1_ACC_B);
  float* out2_acc  = (float*)(ws + OUT2_ACC_B);
  u16*   xn_pad    = (u16*)  (ws + XN_PAD_B);
  u16*   out1n_pad = (u16*)  (ws + OUT1N_PAD_B);
  u16*   Smat      = (u16*)  (ws + S_B);
  u16*   wofft     = (u16*)  (ws + WOFFT_B);
  u16*   wdcnt     = (u16*)  (ws + WDCNT_B);
  u16*   w2t       = (u16*)  (ws + W2T_B);
  int*   pofs      = (int*)  (ws + POFS_B);
  float* pwgt      = (float*)(ws + PWGT_B);
  float* sum1 = stats,       *sq1 = stats + 256;
  float* sum2 = stats + 512, *sq2 = stats + 768;

  hipMemsetAsync(ws, 0, ZERO_BYTES, stream);
  k_x_to_nhwc<<<dim3(64,8,4), 256, 0, stream>>>(in_v, in_i, xn_pad);
  k_prep_woff<<<576, 256, 0, stream>>>(w_off, wofft);
  k_prep_wdcn<<<4608, 256, 0, stream>>>(w_dcn, wdcnt);
  k_prep_w2<<<2304, 256, 0, stream>>>(w2, w2t);
  k_conv_off<<<dim3(128,4), 256, 0, stream>>>(xn_pad, wofft, off_acc);
  k_prep_off2<<<576, 256, 0, stream>>>(off_acc, b_off, pofs, pwgt);
  k_sample<<<dim3(4096,9), 256, 0, stream>>>(xn_pad, pofs, pwgt, Smat);
  k_gemm1<<<dim3(256,2,2), 256, 0, stream>>>(Smat, wdcnt, out1_acc);
  k_stats<<<256, 256, 0, stream>>>(out1_acc, sum1, sq1);
  k_bn1<<<1024, 256, 0, stream>>>(out1_acc, sum1, sq1, g1, bt1, out1n_pad);
  k_gemm2<<<dim3(256,2,2), 256, 0, stream>>>(out1n_pad, w2t, out2_acc);
  k_stats<<<256, 256, 0, stream>>>(out2_acc, sum2, sq2);
  k_bn2_out<<<dim3(64,4,4), 256, 0, stream>>>(out2_acc, sum2, sq2, g2, bt2, out);
}

// Round 7
// 392.499 us; speedup vs baseline: 1.0911x; 1.0911x over previous
//
#include <hip/hip_runtime.h>
#include <cstdint>
#include <cstddef>

typedef unsigned short u16;
typedef __attribute__((ext_vector_type(8))) short s16x8;
typedef __attribute__((ext_vector_type(4))) float f32x4;

#define DEV __device__ __forceinline__

DEV float bf2f(short u){
  union { unsigned int i; float f; } v;
  v.i = ((unsigned int)(u16)u) << 16;
  return v.f;
}
DEV short f2bf(float f){
  union { float f; unsigned int i; } v; v.f = f;
  unsigned int u = v.i;
  u += 0x7fffu + ((u >> 16) & 1u);   // RNE
  return (short)(u >> 16);
}
DEV s16x8 s16x8_zero(){
  s16x8 z;
#pragma unroll
  for(int j=0;j<8;j++) z[j]=0;
  return z;
}
DEV f32x4 f32x4_zero(){
  f32x4 z;
#pragma unroll
  for(int j=0;j<4;j++) z[j]=0.f;
  return z;
}
DEV f32x4 mfma16(s16x8 a, s16x8 b, f32x4 c){
  return __builtin_amdgcn_mfma_f32_16x16x32_bf16(a, b, c, 0, 0, 0);
}
DEV void bar_lds(){
  asm volatile("s_waitcnt lgkmcnt(0)");
  __builtin_amdgcn_s_barrier();
}
// async global -> LDS, 16 B per lane; per-lane global src, lds dst = base + lane*16
DEV void gload16(const u16* g, u16* l){
  __builtin_amdgcn_global_load_lds(
      (const __attribute__((address_space(1))) unsigned int*)g,
      (__attribute__((address_space(3))) unsigned int*)l, 16, 0, 0);
}

// ---------------- problem constants ----------------
// B=4, Cin=512 (concat), H=W=64, P=9 taps, Cout=256, M = B*H*W = 16384
// Padded spatial layouts: [4][66][66][C], zero borders (memset'd).
static constexpr size_t OFF_ACC_B   = 0;                         // float[16384*32]
static constexpr size_t STATS_B     = 2097152;                   // float[1024]
static constexpr size_t OUT1_ACC_B  = 2101248;                   // float[16384*256]
static constexpr size_t OUT2_ACC_B  = 18878464;                  // float[16384*256]
static constexpr size_t XN_PAD_B    = 35655680;                  // u16[4*66*66*512]
static constexpr size_t OUT1N_PAD_B = 53497856;                  // u16[4*66*66*256]
static constexpr size_t ZERO_BYTES  = 62418944;
static constexpr size_t S_B         = 62418944;                  // u16[16384*4608]
static constexpr size_t WOFFT_B     = 213708800;                 // u16[32*4608]
static constexpr size_t WDCNT_B     = 214003712;                 // u16[256*4608]
static constexpr size_t W2T_B       = 216363008;                 // u16[256*2304]
static constexpr size_t POFS_B      = 217542656;                 // int[16384*9*4]
static constexpr size_t PWGT_B      = 219901952;                 // float[16384*9*4]
// total ~212 MB

// ---------------- NCHW fp32 (concat) -> padded NHWC bf16 ----------------
__global__ void k_x_to_nhwc(const float* __restrict__ v, const float* __restrict__ vi,
                            u16* __restrict__ xn){
  __shared__ float tile[64][65];
  const int b = blockIdx.z, c0 = blockIdx.y*64, hw0 = blockIdx.x*64;
  const int h = hw0 >> 6;
  const float* src = (c0 < 256) ? (v  + ((size_t)b*256 + c0)      *4096)
                                : (vi + ((size_t)b*256 + (c0-256))*4096);
  const int t = threadIdx.x;
#pragma unroll
  for(int k=0;k<16;k++){
    int idx = t + k*256;
    int cl = idx >> 6, wl = idx & 63;
    tile[cl][wl] = src[(size_t)cl*4096 + hw0 + wl];
  }
  __syncthreads();
#pragma unroll
  for(int k=0;k<16;k++){
    int idx = t + k*256;
    int wl = idx >> 6, cl = idx & 63;
    xn[((size_t)(b*66 + h+1)*66 + wl+1)*512 + c0 + cl] = (u16)f2bf(tile[cl][wl]);
  }
}

// ---------------- weight repacks: OIHW fp32 -> [N][K] bf16, K = tap*C + c ----------------
__global__ void k_prep_woff(const float* __restrict__ w, u16* __restrict__ wt){
  int idx = blockIdx.x*256 + threadIdx.x;
  if(idx >= 32*4608) return;
  int n = idx / 4608, k = idx % 4608;
  int t = k >> 9, c = k & 511;
  float val = (n < 27) ? w[(size_t)(n*512 + c)*9 + t] : 0.f;
  wt[idx] = (u16)f2bf(val);
}
__global__ void k_prep_wdcn(const float* __restrict__ w, u16* __restrict__ wt){
  int idx = blockIdx.x*256 + threadIdx.x;
  if(idx >= 256*4608) return;
  int n = idx / 4608, k = idx % 4608;
  int t = k >> 9, c = k & 511;
  wt[idx] = (u16)f2bf(w[(size_t)(n*512 + c)*9 + t]);
}
__global__ void k_prep_w2(const float* __restrict__ w, u16* __restrict__ wt){
  int idx = blockIdx.x*256 + threadIdx.x;
  if(idx >= 256*2304) return;
  int n = idx / 2304, k = idx % 2304;
  int t = k >> 8, c = k & 255;
  wt[idx] = (u16)f2bf(w[(size_t)(n*256 + c)*9 + t]);
}

// ---------------- offset conv: 512ch -> 27(pad 32), implicit GEMM (padded input) --------
__global__ __launch_bounds__(256, 2) void k_conv_off(
    const u16* __restrict__ xn, const u16* __restrict__ wt, float* __restrict__ offa){
  __shared__ short A_lds[4][128][8];
  __shared__ short B_lds[4][32][8];
  const int tid = threadIdx.x;
  const int lane = tid & 63, wid = tid >> 6;
  const int quad = lane >> 4, ln = lane & 15;
  const int m0 = blockIdx.x * 128;
  const int b = m0 >> 12;
  const int h0 = (m0 & 4095) >> 6;
  const int ks = blockIdx.y;
  const int ts0 = (ks == 3) ? 6 : ks*2;
  const int ntap = (ks == 3) ? 3 : 2;
  const int m_base = wid * 32;
  const int r = tid >> 1, sp = (tid & 1) * 2;
  const int h_r = h0 + (r >> 6), w_r = r & 63;
  const s16x8* Ap = (const s16x8*)A_lds;
  const s16x8* Bp = (const s16x8*)B_lds;
  f32x4 acc[2][2];
#pragma unroll
  for(int mf=0;mf<2;mf++)
#pragma unroll
    for(int nf=0;nf<2;nf++) acc[mf][nf] = f32x4_zero();

  auto load_it = [&](int it, s16x8& v0, s16x8& v1, s16x8& bv){
    const int tp = ts0 + (it >> 4);
    const int cA = (it & 15)*32;
    const int ty = tp/3, tx = tp - ty*3;
    const int y = h_r + ty, x = w_r + tx;
    const u16* src = xn + ((size_t)(b*66 + y)*66 + x)*512 + cA + sp*8;
    v0 = *(const s16x8*)(src);
    v1 = *(const s16x8*)(src + 8);
    if(tid < 128){
      const int n = tid & 31, s2 = tid >> 5;
      bv = *(const s16x8*)(wt + (size_t)n*4608 + tp*512 + cA + s2*8);
    }
  };

  const int NIT = ntap * 16;
  s16x8 v0a, v1a, bva, v0b, v1b, bvb;
  bva = s16x8_zero(); bvb = s16x8_zero();
  load_it(0, v0a, v1a, bva);
  load_it(1, v0b, v1b, bvb);
  for(int it = 0; it < NIT; it += 2){
    bar_lds();
    *(s16x8*)(&A_lds[sp][r][0])   = v0a;
    *(s16x8*)(&A_lds[sp+1][r][0]) = v1a;
    if(tid < 128){
      const int n = tid & 31, s2 = tid >> 5;
      *(s16x8*)(&B_lds[s2][n][0]) = bva;
    }
    if(it + 2 < NIT) load_it(it + 2, v0a, v1a, bva);
    bar_lds();
    {
      s16x8 a0 = Ap[quad*128 + m_base + ln];
      s16x8 a1 = Ap[quad*128 + m_base + 16 + ln];
      s16x8 b0 = Bp[quad*32 + ln];
      s16x8 b1 = Bp[quad*32 + 16 + ln];
      acc[0][0] = mfma16(a0, b0, acc[0][0]);
      acc[0][1] = mfma16(a0, b1, acc[0][1]);
      acc[1][0] = mfma16(a1, b0, acc[1][0]);
      acc[1][1] = mfma16(a1, b1, acc[1][1]);
    }
    bar_lds();
    *(s16x8*)(&A_lds[sp][r][0])   = v0b;
    *(s16x8*)(&A_lds[sp+1][r][0]) = v1b;
    if(tid < 128){
      const int n = tid & 31, s2 = tid >> 5;
      *(s16x8*)(&B_lds[s2][n][0]) = bvb;
    }
    if(it + 3 < NIT) load_it(it + 3, v0b, v1b, bvb);
    bar_lds();
    {
      s16x8 a0 = Ap[quad*128 + m_base + ln];
      s16x8 a1 = Ap[quad*128 + m_base + 16 + ln];
      s16x8 b0 = Bp[quad*32 + ln];
      s16x8 b1 = Bp[quad*32 + 16 + ln];
      acc[0][0] = mfma16(a0, b0, acc[0][0]);
      acc[0][1] = mfma16(a0, b1, acc[0][1]);
      acc[1][0] = mfma16(a1, b0, acc[1][0]);
      acc[1][1] = mfma16(a1, b1, acc[1][1]);
    }
  }
#pragma unroll
  for(int mf=0;mf<2;mf++)
#pragma unroll
    for(int nf=0;nf<2;nf++){
      const int col = nf*16 + ln;
#pragma unroll
      for(int i=0;i<4;i++){
        const int row = m_base + mf*16 + quad*4 + i;
        unsafeAtomicAdd(offa + (size_t)(m0+row)*32 + col, acc[mf][nf][i]);
      }
    }
}

// ---------------- precompute bilinear offsets/weights -> global ----------------
__global__ void k_prep_off2(const float* __restrict__ offa, const float* __restrict__ boff,
                            int* __restrict__ pofs, float* __restrict__ pwgt){
  int id = blockIdx.x*256 + threadIdx.x;
  if(id >= 16384*9) return;
  int m = id / 9, tp = id - m*9;
  int b = m >> 12, h = (m >> 6) & 63, w = m & 63;
  const float* orow = offa + (size_t)m*32;
  float dy = orow[2*tp]   + boff[2*tp];
  float dx = orow[2*tp+1] + boff[2*tp+1];
  float mz = orow[18+tp]  + boff[18+tp];
  float mk = 1.f / (1.f + expf(-mz));
  float ypos = (float)(h - 1 + tp/3) + dy;
  float xpos = (float)(w - 1 + tp%3) + dx;
  float y0f = floorf(ypos), x0f = floorf(xpos);
  float ly = ypos - y0f, lx = xpos - x0f;
  int y0 = (int)y0f, x0 = (int)x0f;
#pragma unroll
  for(int k=0;k<4;k++){
    int ddy = k >> 1, ddx = k & 1;
    int yi = y0 + ddy, xi = x0 + ddx;
    int yc = yi < -1 ? -1 : (yi > 64 ? 64 : yi);
    int xc = xi < -1 ? -1 : (xi > 64 ? 64 : xi);
    float wk = (ddy ? ly : 1.f-ly) * (ddx ? lx : 1.f-lx) * mk;
    pofs[id*4+k] = ((b*66 + yc+1)*66 + xc+1) << 9;   // *512 channels
    pwgt[id*4+k] = wk;
  }
}

// ---------------- sample+blend: materialize im2col S[16384][4608] bf16 ----------------
__global__ __launch_bounds__(256) void k_sample(
    const u16* __restrict__ xn, const int* __restrict__ pofs,
    const float* __restrict__ pwgt, u16* __restrict__ S){
  const int wid = threadIdx.x >> 6, lane = threadIdx.x & 63;
  const int m = blockIdx.x*4 + wid;
  const int tp = blockIdx.y;
  const int id4 = (m*9 + tp)*4;
  const int4   of = *(const int4*)  (pofs + id4);
  const float4 wg = *(const float4*)(pwgt + id4);
  const int c0 = lane*8;
  s16x8 g0 = *(const s16x8*)(xn + of.x + c0);
  s16x8 g1 = *(const s16x8*)(xn + of.y + c0);
  s16x8 g2 = *(const s16x8*)(xn + of.z + c0);
  s16x8 g3 = *(const s16x8*)(xn + of.w + c0);
  s16x8 pk;
#pragma unroll
  for(int j=0;j<8;j++){
    float f = wg.x * bf2f(g0[j]);
    f = fmaf(wg.y, bf2f(g1[j]), f);
    f = fmaf(wg.z, bf2f(g2[j]), f);
    f = fmaf(wg.w, bf2f(g3[j]), f);
    pk[j] = f2bf(f);
  }
  *(s16x8*)(S + (size_t)m*4608 + tp*512 + c0) = pk;
}

// ---------------- GEMM1: out1 = S[16384][4608] x WdcnT[256][4608]^T ----------------
// 128x128 tile, BK=64, DOUBLE-buffered LDS (64KB), counted vmcnt(8) — loads stay
// in flight across barriers (T3/T4). grid (128,2,2) = 512 blocks = 2/CU.
__global__ __launch_bounds__(256, 2) void k_gemm1(
    const u16* __restrict__ S, const u16* __restrict__ wt, float* __restrict__ outa){
  __shared__ short A_lds[2][8][128][8];   // 32 KB [buf][k-slice][m-row][8]
  __shared__ short B_lds[2][8][128][8];   // 32 KB [buf][k-slice][n-row][8]
  const int tid = threadIdx.x;
  const int lane = tid & 63, wid = tid >> 6;
  const int quad = lane >> 4, ln = lane & 15;
  const int wm = wid >> 1, wn = wid & 1;       // 2x2 waves, 64x64 each
  const int m0 = blockIdx.x * 128;
  const int n0 = blockIdx.y * 128;
  const int kbase = blockIdx.z * 2304;
  constexpr int NPH = 36;
  f32x4 acc[4][4];
#pragma unroll
  for(int mf=0;mf<4;mf++)
#pragma unroll
    for(int nf=0;nf<4;nf++) acc[mf][nf] = f32x4_zero();

  auto stage = [&](int t, int bi){              // 8 gload16 per wave (4 A + 4 B)
    const int k0 = kbase + t*64;
#pragma unroll
    for(int i=0;i<4;i++){
      const int idx = wid*4 + i;                // 0..15
      const int s = idx >> 1, rh = (idx & 1)*64;
      gload16(S  + (size_t)(m0 + rh + lane)*4608 + k0 + s*8, (u16*)&A_lds[bi][s][rh][0]);
      gload16(wt + (size_t)(n0 + rh + lane)*4608 + k0 + s*8, (u16*)&B_lds[bi][s][rh][0]);
    }
  };
  auto compute = [&](int bi){                   // 32 MFMA per wave
#pragma unroll
    for(int kk=0;kk<2;kk++){
      s16x8 af[4], bf[4];
#pragma unroll
      for(int mf=0;mf<4;mf++)
        af[mf] = *(const s16x8*)&A_lds[bi][kk*4+quad][wm*64 + mf*16 + ln][0];
#pragma unroll
      for(int nf=0;nf<4;nf++)
        bf[nf] = *(const s16x8*)&B_lds[bi][kk*4+quad][wn*64 + nf*16 + ln][0];
#pragma unroll
      for(int mf=0;mf<4;mf++)
#pragma unroll
        for(int nf=0;nf<4;nf++)
          acc[mf][nf] = mfma16(af[mf], bf[nf], acc[mf][nf]);
    }
  };

  stage(0, 0);
  asm volatile("s_waitcnt vmcnt(0)");
  __builtin_amdgcn_s_barrier();
  stage(1, 1);                                  // in flight across the loop barriers
  for(int t = 0; t < NPH; ++t){
    const int bi = t & 1;
    compute(bi);
    bar_lds();                                  // all waves done reading buf bi
    if(t + 2 < NPH){
      stage(t + 2, bi);                         // overwrite just-freed buffer
      asm volatile("s_waitcnt vmcnt(8)");       // stage(t+1) landed; t+2 in flight
    } else {
      asm volatile("s_waitcnt vmcnt(0)");
    }
    __builtin_amdgcn_sched_barrier(0);
    __builtin_amdgcn_s_barrier();               // stage(t+1) visible to all waves
  }

#pragma unroll
  for(int mf=0;mf<4;mf++)
#pragma unroll
    for(int nf=0;nf<4;nf++){
      const int col = n0 + wn*64 + nf*16 + ln;
#pragma unroll
      for(int i=0;i<4;i++){
        const int row = m0 + wm*64 + mf*16 + quad*4 + i;
        unsafeAtomicAdd(outa + (size_t)row*256 + col, acc[mf][nf][i]);
      }
    }
}

// ---------------- GEMM2: out2 = im2col(out1n_pad)[16384][2304] x W2T[256][2304]^T ------
// same dbuf + counted-vmcnt structure; A staged from padded activations.
__global__ __launch_bounds__(256, 2) void k_gemm2(
    const u16* __restrict__ a_pad, const u16* __restrict__ wt, float* __restrict__ outa){
  __shared__ short A_lds[2][8][128][8];   // 32 KB
  __shared__ short B_lds[2][8][128][8];   // 32 KB
  const int tid = threadIdx.x;
  const int lane = tid & 63, wid = tid >> 6;
  const int quad = lane >> 4, ln = lane & 15;
  const int wm = wid >> 1, wn = wid & 1;
  const int m0 = blockIdx.x * 128;
  const int n0 = blockIdx.y * 128;
  const int kbase = blockIdx.z * 1152;
  const int b = m0 >> 12;
  const int h0 = (m0 & 4095) >> 6;
  constexpr int NPH = 18;
  f32x4 acc[4][4];
#pragma unroll
  for(int mf=0;mf<4;mf++)
#pragma unroll
    for(int nf=0;nf<4;nf++) acc[mf][nf] = f32x4_zero();

  auto stage = [&](int t, int bi){
    const int k0 = kbase + t*64;
    const int tp = k0 >> 8, cit = k0 & 255;
    const int ty = tp/3, tx = tp - ty*3;
#pragma unroll
    for(int i=0;i<4;i++){
      const int idx = wid*4 + i;
      const int s = idx >> 1, rh = (idx & 1)*64;
      const int hh = h0 + (rh >> 6) + ty;       // rh=0 -> h0, rh=64 -> h0+1
      gload16(a_pad + ((size_t)(b*66 + hh)*66 + lane + tx)*256 + cit + s*8,
              (u16*)&A_lds[bi][s][rh][0]);
      gload16(wt + (size_t)(n0 + rh + lane)*2304 + k0 + s*8,
              (u16*)&B_lds[bi][s][rh][0]);
    }
  };
  auto compute = [&](int bi){
#pragma unroll
    for(int kk=0;kk<2;kk++){
      s16x8 af[4], bf[4];
#pragma unroll
      for(int mf=0;mf<4;mf++)
        af[mf] = *(const s16x8*)&A_lds[bi][kk*4+quad][wm*64 + mf*16 + ln][0];
#pragma unroll
      for(int nf=0;nf<4;nf++)
        bf[nf] = *(const s16x8*)&B_lds[bi][kk*4+quad][wn*64 + nf*16 + ln][0];
#pragma unroll
      for(int mf=0;mf<4;mf++)
#pragma unroll
        for(int nf=0;nf<4;nf++)
          acc[mf][nf] = mfma16(af[mf], bf[nf], acc[mf][nf]);
    }
  };

  stage(0, 0);
  asm volatile("s_waitcnt vmcnt(0)");
  __builtin_amdgcn_s_barrier();
  stage(1, 1);
  for(int t = 0; t < NPH; ++t){
    const int bi = t & 1;
    compute(bi);
    bar_lds();
    if(t + 2 < NPH){
      stage(t + 2, bi);
      asm volatile("s_waitcnt vmcnt(8)");
    } else {
      asm volatile("s_waitcnt vmcnt(0)");
    }
    __builtin_amdgcn_sched_barrier(0);
    __builtin_amdgcn_s_barrier();
  }

#pragma unroll
  for(int mf=0;mf<4;mf++)
#pragma unroll
    for(int nf=0;nf<4;nf++){
      const int col = n0 + wn*64 + nf*16 + ln;
#pragma unroll
      for(int i=0;i<4;i++){
        const int row = m0 + wm*64 + mf*16 + quad*4 + i;
        unsafeAtomicAdd(outa + (size_t)row*256 + col, acc[mf][nf][i]);
      }
    }
}

// ---------------- BN stats: per-channel sum/sumsq over M=16384 ----------------
__global__ void k_stats(const float* __restrict__ acc, float* __restrict__ sum,
                        float* __restrict__ sq){
  const int m0 = blockIdx.x*64;
  const int c = threadIdx.x;
  float s = 0.f, q = 0.f;
  for(int i=0;i<64;i++){
    float v = acc[(size_t)(m0+i)*256 + c];
    s += v; q += v*v;
  }
  unsafeAtomicAdd(sum + c, s);
  unsafeAtomicAdd(sq + c, q);
}

// ---------------- BN1 + ReLU -> padded bf16 NHWC ----------------
__global__ void k_bn1(const float* __restrict__ acc, const float* __restrict__ sum,
                      const float* __restrict__ sq, const float* __restrict__ g,
                      const float* __restrict__ bt, u16* __restrict__ o){
  __shared__ float sc[256], sh[256];
  const int t = threadIdx.x;
  {
    float mean = sum[t] * (1.f/16384.f);
    float var  = sq[t] * (1.f/16384.f) - mean*mean;
    float rstd = rsqrtf(var + 1e-5f);
    float s = g[t] * rstd;
    sc[t] = s; sh[t] = bt[t] - mean*s;
  }
  __syncthreads();
  const int c4 = (t & 63) * 4;
  const float s0 = sc[c4], s1 = sc[c4+1], s2 = sc[c4+2], s3 = sc[c4+3];
  const float h0 = sh[c4], h1 = sh[c4+1], h2 = sh[c4+2], h3 = sh[c4+3];
#pragma unroll
  for(int k=0;k<4;k++){
    int m = blockIdx.x*16 + k*4 + (t>>6);
    int b = m >> 12, hh = (m >> 6) & 63, ww = m & 63;
    const float4 v = *(const float4*)(acc + (size_t)m*256 + c4);
    unsigned int lo = (unsigned int)(u16)f2bf(fmaxf(0.f, v.x*s0 + h0))
                    | ((unsigned int)(u16)f2bf(fmaxf(0.f, v.y*s1 + h1)) << 16);
    unsigned int hi = (unsigned int)(u16)f2bf(fmaxf(0.f, v.z*s2 + h2))
                    | ((unsigned int)(u16)f2bf(fmaxf(0.f, v.w*s3 + h3)) << 16);
    uint2 pr; pr.x = lo; pr.y = hi;
    *(uint2*)(o + ((size_t)(b*66 + hh+1)*66 + ww+1)*256 + c4) = pr;
  }
}

// ---------------- BN2 + ReLU + NHWC->NCHW fp32 output ----------------
__global__ void k_bn2_out(const float* __restrict__ acc, const float* __restrict__ sum,
                          const float* __restrict__ sq, const float* __restrict__ g,
                          const float* __restrict__ bt, float* __restrict__ out){
  __shared__ float tile[64][65];
  __shared__ float sc[64], sh[64];
  const int t = threadIdx.x;
  const int b = blockIdx.z, c0 = blockIdx.y*64, hw0 = blockIdx.x*64;
  if(t < 64){
    int c = c0 + t;
    float mean = sum[c] * (1.f/16384.f);
    float var  = sq[c] * (1.f/16384.f) - mean*mean;
    float rstd = rsqrtf(var + 1e-5f);
    float s = g[c] * rstd;
    sc[t] = s; sh[t] = bt[c] - mean*s;
  }
  __syncthreads();
#pragma unroll
  for(int k=0;k<16;k++){
    int idx = t + k*256;
    int wl = idx >> 6, cl = idx & 63;
    float v = acc[(size_t)((b<<12) + hw0 + wl)*256 + c0 + cl];
    tile[wl][cl] = fmaxf(0.f, v*sc[cl] + sh[cl]);
  }
  __syncthreads();
#pragma unroll
  for(int k=0;k<16;k++){
    int idx = t + k*256;
    int cl = idx >> 6, wl = idx & 63;
    out[(size_t)(b*256 + c0 + cl)*4096 + hw0 + wl] = tile[wl][cl];
  }
}

extern "C" void kernel_launch(void* const* d_in, const int* in_sizes, int n_in,
                              void* d_out, int out_size, void* d_ws, size_t ws_size,
                              hipStream_t stream){
  const float* in_v  = (const float*)d_in[0];
  const float* in_i  = (const float*)d_in[1];
  const float* w_off = (const float*)d_in[2];
  const float* b_off = (const float*)d_in[3];
  const float* w_dcn = (const float*)d_in[4];
  const float* g1    = (const float*)d_in[5];
  const float* bt1   = (const float*)d_in[6];
  const float* w2    = (const float*)d_in[7];
  const float* g2    = (const float*)d_in[8];
  const float* bt2   = (const float*)d_in[9];
  float* out = (float*)d_out;
  char* ws = (char*)d_ws;

  float* off_acc   = (float*)(ws + OFF_ACC_B);
  float* stats     = (float*)(ws + STATS_B);
  float* out1_acc  = (float*)(ws + OUT1_ACC_B);
  float* out2_acc  = (float*)(ws + OUT2_ACC_B);
  u16*   xn_pad    = (u16*)  (ws + XN_PAD_B);
  u16*   out1n_pad = (u16*)  (ws + OUT1N_PAD_B);
  u16*   Smat      = (u16*)  (ws + S_B);
  u16*   wofft     = (u16*)  (ws + WOFFT_B);
  u16*   wdcnt     = (u16*)  (ws + WDCNT_B);
  u16*   w2t       = (u16*)  (ws + W2T_B);
  int*   pofs      = (int*)  (ws + POFS_B);
  float* pwgt      = (float*)(ws + PWGT_B);
  float* sum1 = stats,       *sq1 = stats + 256;
  float* sum2 = stats + 512, *sq2 = stats + 768;

  hipMemsetAsync(ws, 0, ZERO_BYTES, stream);
  k_x_to_nhwc<<<dim3(64,8,4), 256, 0, stream>>>(in_v, in_i, xn_pad);
  k_prep_woff<<<576, 256, 0, stream>>>(w_off, wofft);
  k_prep_wdcn<<<4608, 256, 0, stream>>>(w_dcn, wdcnt);
  k_prep_w2<<<2304, 256, 0, stream>>>(w2, w2t);
  k_conv_off<<<dim3(128,4), 256, 0, stream>>>(xn_pad, wofft, off_acc);
  k_prep_off2<<<576, 256, 0, stream>>>(off_acc, b_off, pofs, pwgt);
  k_sample<<<dim3(4096,9), 256, 0, stream>>>(xn_pad, pofs, pwgt, Smat);
  k_gemm1<<<dim3(128,2,2), 256, 0, stream>>>(Smat, wdcnt, out1_acc);
  k_stats<<<256, 256, 0, stream>>>(out1_acc, sum1, sq1);
  k_bn1<<<1024, 256, 0, stream>>>(out1_acc, sum1, sq1, g1, bt1, out1n_pad);
  k_gemm2<<<dim3(128,2,2), 256, 0, stream>>>(out1n_pad, w2t, out2_acc);
  k_stats<<<256, 256, 0, stream>>>(out2_acc, sum2, sq2);
  k_bn2_out<<<dim3(64,4,4), 256, 0, stream>>>(out2_acc, sum2, sq2, g2, bt2, out);
}

// Round 9
// 376.353 us; speedup vs baseline: 1.1379x; 1.0429x over previous
//
#include <hip/hip_runtime.h>
#include <cstdint>
#include <cstddef>

typedef unsigned short u16;
typedef __attribute__((ext_vector_type(8))) short s16x8;
typedef __attribute__((ext_vector_type(4))) float f32x4;

#define DEV __device__ __forceinline__

DEV float bf2f(short u){
  union { unsigned int i; float f; } v;
  v.i = ((unsigned int)(u16)u) << 16;
  return v.f;
}
DEV short f2bf(float f){
  union { float f; unsigned int i; } v; v.f = f;
  unsigned int u = v.i;
  u += 0x7fffu + ((u >> 16) & 1u);   // RNE
  return (short)(u >> 16);
}
DEV s16x8 s16x8_zero(){
  s16x8 z;
#pragma unroll
  for(int j=0;j<8;j++) z[j]=0;
  return z;
}
DEV f32x4 f32x4_zero(){
  f32x4 z;
#pragma unroll
  for(int j=0;j<4;j++) z[j]=0.f;
  return z;
}
DEV f32x4 mfma16(s16x8 a, s16x8 b, f32x4 c){
  return __builtin_amdgcn_mfma_f32_16x16x32_bf16(a, b, c, 0, 0, 0);
}
DEV void bar_lds(){
  asm volatile("s_waitcnt lgkmcnt(0)" ::: "memory");
  __builtin_amdgcn_s_barrier();
}
// async global -> LDS, 16 B per lane; per-lane global src, lds dst = base + lane*16
DEV void gload16(const u16* g, u16* l){
  __builtin_amdgcn_global_load_lds(
      (const __attribute__((address_space(1))) unsigned int*)g,
      (__attribute__((address_space(3))) unsigned int*)l, 16, 0, 0);
}

// ---------------- problem constants ----------------
// B=4, Cin=512 (concat), H=W=64, P=9 taps, Cout=256, M = B*H*W = 16384
// Padded spatial layouts: [4][66][66][C], zero borders (memset'd).
static constexpr size_t OFF_ACC_B   = 0;                         // float[16384*32]
static constexpr size_t STATS_B     = 2097152;                   // float[1024]
static constexpr size_t OUT1_ACC_B  = 2101248;                   // float[16384*256]
static constexpr size_t OUT2_ACC_B  = 18878464;                  // float[16384*256]
static constexpr size_t XN_PAD_B    = 35655680;                  // u16[4*66*66*512]
static constexpr size_t OUT1N_PAD_B = 53497856;                  // u16[4*66*66*256]
static constexpr size_t ZERO_BYTES  = 62418944;
static constexpr size_t WOFFT_B     = 213708800;                 // u16[32*4608]
static constexpr size_t WDCNT_B     = 214003712;                 // u16[256*4608]
static constexpr size_t W2T_B       = 216363008;                 // u16[256*2304]
static constexpr size_t POFS_B      = 217542656;                 // int[16384*9*4]
static constexpr size_t PWGT_B      = 219901952;                 // float[16384*9*4]

// ---------------- NCHW fp32 (concat) -> padded NHWC bf16 ----------------
__global__ void k_x_to_nhwc(const float* __restrict__ v, const float* __restrict__ vi,
                            u16* __restrict__ xn){
  __shared__ float tile[64][65];
  const int b = blockIdx.z, c0 = blockIdx.y*64, hw0 = blockIdx.x*64;
  const int h = hw0 >> 6;
  const float* src = (c0 < 256) ? (v  + ((size_t)b*256 + c0)      *4096)
                                : (vi + ((size_t)b*256 + (c0-256))*4096);
  const int t = threadIdx.x;
#pragma unroll
  for(int k=0;k<16;k++){
    int idx = t + k*256;
    int cl = idx >> 6, wl = idx & 63;
    tile[cl][wl] = src[(size_t)cl*4096 + hw0 + wl];
  }
  __syncthreads();
#pragma unroll
  for(int k=0;k<16;k++){
    int idx = t + k*256;
    int wl = idx >> 6, cl = idx & 63;
    xn[((size_t)(b*66 + h+1)*66 + wl+1)*512 + c0 + cl] = (u16)f2bf(tile[cl][wl]);
  }
}

// ---------------- weight repacks: OIHW fp32 -> [N][K] bf16, K = tap*C + c ----------------
__global__ void k_prep_woff(const float* __restrict__ w, u16* __restrict__ wt){
  int idx = blockIdx.x*256 + threadIdx.x;
  if(idx >= 32*4608) return;
  int n = idx / 4608, k = idx % 4608;
  int t = k >> 9, c = k & 511;
  float val = (n < 27) ? w[(size_t)(n*512 + c)*9 + t] : 0.f;
  wt[idx] = (u16)f2bf(val);
}
__global__ void k_prep_wdcn(const float* __restrict__ w, u16* __restrict__ wt){
  int idx = blockIdx.x*256 + threadIdx.x;
  if(idx >= 256*4608) return;
  int n = idx / 4608, k = idx % 4608;
  int t = k >> 9, c = k & 511;
  wt[idx] = (u16)f2bf(w[(size_t)(n*512 + c)*9 + t]);
}
__global__ void k_prep_w2(const float* __restrict__ w, u16* __restrict__ wt){
  int idx = blockIdx.x*256 + threadIdx.x;
  if(idx >= 256*2304) return;
  int n = idx / 2304, k = idx % 2304;
  int t = k >> 8, c = k & 255;
  wt[idx] = (u16)f2bf(w[(size_t)(n*256 + c)*9 + t]);
}

// ---------------- offset conv: 512ch -> 27(pad 32), implicit GEMM (padded input) --------
__global__ __launch_bounds__(256, 2) void k_conv_off(
    const u16* __restrict__ xn, const u16* __restrict__ wt, float* __restrict__ offa){
  __shared__ short A_lds[4][128][8];
  __shared__ short B_lds[4][32][8];
  const int tid = threadIdx.x;
  const int lane = tid & 63, wid = tid >> 6;
  const int quad = lane >> 4, ln = lane & 15;
  const int m0 = blockIdx.x * 128;
  const int b = m0 >> 12;
  const int h0 = (m0 & 4095) >> 6;
  const int ks = blockIdx.y;
  const int ts0 = (ks == 3) ? 6 : ks*2;
  const int ntap = (ks == 3) ? 3 : 2;
  const int m_base = wid * 32;
  const int r = tid >> 1, sp = (tid & 1) * 2;
  const int h_r = h0 + (r >> 6), w_r = r & 63;
  const s16x8* Ap = (const s16x8*)A_lds;
  const s16x8* Bp = (const s16x8*)B_lds;
  f32x4 acc[2][2];
#pragma unroll
  for(int mf=0;mf<2;mf++)
#pragma unroll
    for(int nf=0;nf<2;nf++) acc[mf][nf] = f32x4_zero();

  auto load_it = [&](int it, s16x8& v0, s16x8& v1, s16x8& bv){
    const int tp = ts0 + (it >> 4);
    const int cA = (it & 15)*32;
    const int ty = tp/3, tx = tp - ty*3;
    const int y = h_r + ty, x = w_r + tx;
    const u16* src = xn + ((size_t)(b*66 + y)*66 + x)*512 + cA + sp*8;
    v0 = *(const s16x8*)(src);
    v1 = *(const s16x8*)(src + 8);
    if(tid < 128){
      const int n = tid & 31, s2 = tid >> 5;
      bv = *(const s16x8*)(wt + (size_t)n*4608 + tp*512 + cA + s2*8);
    }
  };

  const int NIT = ntap * 16;
  s16x8 v0a, v1a, bva, v0b, v1b, bvb;
  bva = s16x8_zero(); bvb = s16x8_zero();
  load_it(0, v0a, v1a, bva);
  load_it(1, v0b, v1b, bvb);
  for(int it = 0; it < NIT; it += 2){
    bar_lds();
    *(s16x8*)(&A_lds[sp][r][0])   = v0a;
    *(s16x8*)(&A_lds[sp+1][r][0]) = v1a;
    if(tid < 128){
      const int n = tid & 31, s2 = tid >> 5;
      *(s16x8*)(&B_lds[s2][n][0]) = bva;
    }
    if(it + 2 < NIT) load_it(it + 2, v0a, v1a, bva);
    bar_lds();
    {
      s16x8 a0 = Ap[quad*128 + m_base + ln];
      s16x8 a1 = Ap[quad*128 + m_base + 16 + ln];
      s16x8 b0 = Bp[quad*32 + ln];
      s16x8 b1 = Bp[quad*32 + 16 + ln];
      acc[0][0] = mfma16(a0, b0, acc[0][0]);
      acc[0][1] = mfma16(a0, b1, acc[0][1]);
      acc[1][0] = mfma16(a1, b0, acc[1][0]);
      acc[1][1] = mfma16(a1, b1, acc[1][1]);
    }
    bar_lds();
    *(s16x8*)(&A_lds[sp][r][0])   = v0b;
    *(s16x8*)(&A_lds[sp+1][r][0]) = v1b;
    if(tid < 128){
      const int n = tid & 31, s2 = tid >> 5;
      *(s16x8*)(&B_lds[s2][n][0]) = bvb;
    }
    if(it + 3 < NIT) load_it(it + 3, v0b, v1b, bvb);
    bar_lds();
    {
      s16x8 a0 = Ap[quad*128 + m_base + ln];
      s16x8 a1 = Ap[quad*128 + m_base + 16 + ln];
      s16x8 b0 = Bp[quad*32 + ln];
      s16x8 b1 = Bp[quad*32 + 16 + ln];
      acc[0][0] = mfma16(a0, b0, acc[0][0]);
      acc[0][1] = mfma16(a0, b1, acc[0][1]);
      acc[1][0] = mfma16(a1, b0, acc[1][0]);
      acc[1][1] = mfma16(a1, b1, acc[1][1]);
    }
  }
#pragma unroll
  for(int mf=0;mf<2;mf++)
#pragma unroll
    for(int nf=0;nf<2;nf++){
      const int col = nf*16 + ln;
#pragma unroll
      for(int i=0;i<4;i++){
        const int row = m_base + mf*16 + quad*4 + i;
        unsafeAtomicAdd(offa + (size_t)(m0+row)*32 + col, acc[mf][nf][i]);
      }
    }
}

// ---------------- precompute bilinear offsets/weights -> global ----------------
__global__ void k_prep_off2(const float* __restrict__ offa, const float* __restrict__ boff,
                            int* __restrict__ pofs, float* __restrict__ pwgt){
  int id = blockIdx.x*256 + threadIdx.x;
  if(id >= 16384*9) return;
  int m = id / 9, tp = id - m*9;
  int b = m >> 12, h = (m >> 6) & 63, w = m & 63;
  const float* orow = offa + (size_t)m*32;
  float dy = orow[2*tp]   + boff[2*tp];
  float dx = orow[2*tp+1] + boff[2*tp+1];
  float mz = orow[18+tp]  + boff[18+tp];
  float mk = 1.f / (1.f + expf(-mz));
  float ypos = (float)(h - 1 + tp/3) + dy;
  float xpos = (float)(w - 1 + tp%3) + dx;
  float y0f = floorf(ypos), x0f = floorf(xpos);
  float ly = ypos - y0f, lx = xpos - x0f;
  int y0 = (int)y0f, x0 = (int)x0f;
#pragma unroll
  for(int k=0;k<4;k++){
    int ddy = k >> 1, ddx = k & 1;
    int yi = y0 + ddy, xi = x0 + ddx;
    int yc = yi < -1 ? -1 : (yi > 64 ? 64 : yi);
    int xc = xi < -1 ? -1 : (xi > 64 ? 64 : xi);
    float wk = (ddy ? ly : 1.f-ly) * (ddx ? lx : 1.f-lx) * mk;
    pofs[id*4+k] = ((b*66 + yc+1)*66 + xc+1) << 9;   // *512 channels
    pwgt[id*4+k] = wk;
  }
}

// ---------------- DCN producer-consumer: fused sample + GEMM (reg-staged, T14) ---------
// 256 blocks (one 64-row m-tile each, XCD-swizzled), 512 threads.
// Waves 0-3 produce: B global->reg (1 window ahead) -> ds_write; A gather->blend->ds_write.
// Waves 4-7 consume: MFMA. ALL LDS traffic is ds_write; bar_lds (lgkmcnt+barrier) is a
// complete fence — no manual vmcnt counting anywhere (R8's race class eliminated).
__global__ __launch_bounds__(512, 1) void k_dcn_pc(
    const u16* __restrict__ xn, const u16* __restrict__ wt,
    const int* __restrict__ pofs, const float* __restrict__ pwgt,
    float* __restrict__ outa){
  __shared__ short A_lds[2][8][64][8];    // 16 KB [buf][k-slice][m-row][8]
  __shared__ short B_lds[2][8][256][8];   // 64 KB [buf][k-slice][n-row][8]
  __shared__ int   s_ofs[9][4][64];       // 9 KB
  __shared__ float s_wgt[9][4][64];       // 9 KB
  const int tid = threadIdx.x;
  const int lane = tid & 63, wid = tid >> 6;
  const int quad = lane >> 4, ln = lane & 15;
  const int bid = blockIdx.x;
  const int mb = (bid & 7)*32 + (bid >> 3);   // bijective XCD swizzle (256 = 8*32)
  const int m0 = mb * 64;
  constexpr int NP = 72;                      // 9 taps x 8 chunks of 64 ch

  // one-time: bilinear tables -> LDS (all threads)
  for(int i = tid; i < 576; i += 512){
    const int rr = i & 63, tp = i >> 6;
    const int id4 = ((m0 + rr)*9 + tp)*4;
    int4   of = *(const int4*)  (pofs + id4);
    float4 wg = *(const float4*)(pwgt + id4);
    s_ofs[tp][0][rr] = of.x; s_ofs[tp][1][rr] = of.y;
    s_ofs[tp][2][rr] = of.z; s_ofs[tp][3][rr] = of.w;
    s_wgt[tp][0][rr] = wg.x; s_wgt[tp][1][rr] = wg.y;
    s_wgt[tp][2][rr] = wg.z; s_wgt[tp][3][rr] = wg.w;
  }
  __syncthreads();

  if(wid < 4){
    // ---------------- producer waves ----------------
    const int wl = wid;
    const int r  = wl*16 + (lane >> 2);       // A m-row this lane produces
    const int k8 = (lane & 3)*2;              // two adjacent k-octs
    s16x8 G[8];                               // A gathers: 4 neighbors x 2 octs
    s16x8 Bv[8];                              // B slab: 8 x (k-slice, n0) pieces

    auto bload = [&](int t){                  // B(t) global -> regs (consumed next window)
      const int tp = t >> 3, cc = (t & 7)*64;
#pragma unroll
      for(int i2=0;i2<8;i2++){
        const int idx = wl*8 + i2;            // 0..31 over 4 waves
        const int s = idx >> 2, n0 = (idx & 3)*64;
        Bv[i2] = *(const s16x8*)(wt + (size_t)(n0 + lane)*4608 + tp*512 + cc + s*8);
      }
    };
    auto bwrite = [&](int bi){                // regs -> LDS (implicit wait on bload)
#pragma unroll
      for(int i2=0;i2<8;i2++){
        const int idx = wl*8 + i2;
        const int s = idx >> 2, n0 = (idx & 3)*64;
        *(s16x8*)&B_lds[bi][s][n0 + lane][0] = Bv[i2];
      }
    };
    auto gatherG = [&](int t){                // 8 reg loads (4 neighbors x 2 octs)
      const int tp = t >> 3;
      const int c0 = (t & 7)*64 + k8*8;
#pragma unroll
      for(int k=0;k<4;k++){
        const u16* src = xn + s_ofs[tp][k][r] + c0;
        G[k]   = *(const s16x8*)(src);
        G[4+k] = *(const s16x8*)(src + 8);
      }
    };
    auto blendW = [&](int t, int bi){         // blend G -> 2 ds_write_b128
      const int tp = t >> 3;
      const float w0 = s_wgt[tp][0][r], w1 = s_wgt[tp][1][r];
      const float w2 = s_wgt[tp][2][r], w3 = s_wgt[tp][3][r];
      s16x8 p0, p1;
#pragma unroll
      for(int j=0;j<8;j++){
        float f = w0*bf2f(G[0][j]); f = fmaf(w1, bf2f(G[1][j]), f);
        f = fmaf(w2, bf2f(G[2][j]), f); f = fmaf(w3, bf2f(G[3][j]), f);
        p0[j] = f2bf(f);
        float g = w0*bf2f(G[4][j]); g = fmaf(w1, bf2f(G[5][j]), g);
        g = fmaf(w2, bf2f(G[6][j]), g); g = fmaf(w3, bf2f(G[7][j]), g);
        p1[j] = f2bf(g);
      }
      *(s16x8*)&A_lds[bi][k8][r][0]   = p0;
      *(s16x8*)&A_lds[bi][k8+1][r][0] = p1;
    };

    // warmup: fill buf0; B(1)/G(1) loads in flight across the barrier
    bload(0); gatherG(0);
    bwrite(0); blendW(0, 0);                  // waits its own loads (register deps)
    bload(1); gatherG(1);                     // WAR-ordered after the writes above
    bar_lds();

    for(int t = 0; t < NP; ++t){
      const int nxt = (t + 1) & 1;
      if(t + 1 < NP){
        bwrite(nxt);                          // B(t+1): regs loaded last window
        blendW(t + 1, nxt);                   // A(t+1): gathers from last window
      }
      if(t + 2 < NP){
        bload(t + 2);                         // issue next-window loads (full window
        gatherG(t + 2);                       //  of latency cover; WAR-ordered)
      }
      bar_lds();                              // lgkmcnt(0)+barrier: ds_writes visible
    }
  } else {
    // ---------------- consumer waves ----------------
    const int wn = wid - 4;                   // 64-col slab
    f32x4 acc[4][4];
#pragma unroll
    for(int mf=0;mf<4;mf++)
#pragma unroll
      for(int nf=0;nf<4;nf++) acc[mf][nf] = f32x4_zero();

    bar_lds();                                // matches producer warmup barrier
    for(int t = 0; t < NP; ++t){
      const int bi = t & 1;
#pragma unroll
      for(int kk=0;kk<2;kk++){
        s16x8 af[4], bf[4];
#pragma unroll
        for(int mf=0;mf<4;mf++)
          af[mf] = *(const s16x8*)&A_lds[bi][kk*4+quad][mf*16 + ln][0];
#pragma unroll
        for(int nf=0;nf<4;nf++)
          bf[nf] = *(const s16x8*)&B_lds[bi][kk*4+quad][wn*64 + nf*16 + ln][0];
#pragma unroll
        for(int mf=0;mf<4;mf++)
#pragma unroll
          for(int nf=0;nf<4;nf++)
            acc[mf][nf] = mfma16(af[mf], bf[nf], acc[mf][nf]);
      }
      bar_lds();
    }
    // epilogue: plain stores (full K in-block, no atomics)
#pragma unroll
    for(int mf=0;mf<4;mf++)
#pragma unroll
      for(int nf=0;nf<4;nf++){
        const int col = wn*64 + nf*16 + ln;
#pragma unroll
        for(int i=0;i<4;i++){
          const int row = m0 + mf*16 + quad*4 + i;
          outa[(size_t)row*256 + col] = acc[mf][nf][i];
        }
      }
  }
}

// ---------------- GEMM2: out2 = im2col(out1n_pad)[16384][2304] x W2T[256][2304]^T ------
__global__ __launch_bounds__(256, 2) void k_gemm2(
    const u16* __restrict__ a_pad, const u16* __restrict__ wt, float* __restrict__ outa){
  __shared__ short A_lds[2][8][128][8];   // 32 KB
  __shared__ short B_lds[2][8][128][8];   // 32 KB
  const int tid = threadIdx.x;
  const int lane = tid & 63, wid = tid >> 6;
  const int quad = lane >> 4, ln = lane & 15;
  const int wm = wid >> 1, wn = wid & 1;
  const int m0 = blockIdx.x * 128;
  const int n0 = blockIdx.y * 128;
  const int kbase = blockIdx.z * 1152;
  const int b = m0 >> 12;
  const int h0 = (m0 & 4095) >> 6;
  constexpr int NPH = 18;
  f32x4 acc[4][4];
#pragma unroll
  for(int mf=0;mf<4;mf++)
#pragma unroll
    for(int nf=0;nf<4;nf++) acc[mf][nf] = f32x4_zero();

  auto stage = [&](int t, int bi){
    const int k0 = kbase + t*64;
    const int tp = k0 >> 8, cit = k0 & 255;
    const int ty = tp/3, tx = tp - ty*3;
#pragma unroll
    for(int i=0;i<4;i++){
      const int idx = wid*4 + i;
      const int s = idx >> 1, rh = (idx & 1)*64;
      const int hh = h0 + (rh >> 6) + ty;
      gload16(a_pad + ((size_t)(b*66 + hh)*66 + lane + tx)*256 + cit + s*8,
              (u16*)&A_lds[bi][s][rh][0]);
      gload16(wt + (size_t)(n0 + rh + lane)*2304 + k0 + s*8,
              (u16*)&B_lds[bi][s][rh][0]);
    }
  };
  auto compute = [&](int bi){
#pragma unroll
    for(int kk=0;kk<2;kk++){
      s16x8 af[4], bf[4];
#pragma unroll
      for(int mf=0;mf<4;mf++)
        af[mf] = *(const s16x8*)&A_lds[bi][kk*4+quad][wm*64 + mf*16 + ln][0];
#pragma unroll
      for(int nf=0;nf<4;nf++)
        bf[nf] = *(const s16x8*)&B_lds[bi][kk*4+quad][wn*64 + nf*16 + ln][0];
#pragma unroll
      for(int mf=0;mf<4;mf++)
#pragma unroll
        for(int nf=0;nf<4;nf++)
          acc[mf][nf] = mfma16(af[mf], bf[nf], acc[mf][nf]);
    }
  };

  stage(0, 0);
  asm volatile("s_waitcnt vmcnt(0)" ::: "memory");
  __builtin_amdgcn_s_barrier();
  stage(1, 1);
  for(int t = 0; t < NPH; ++t){
    const int bi = t & 1;
    compute(bi);
    bar_lds();
    if(t + 2 < NPH){
      stage(t + 2, bi);
      asm volatile("s_waitcnt vmcnt(8)" ::: "memory");
    } else {
      asm volatile("s_waitcnt vmcnt(0)" ::: "memory");
    }
    __builtin_amdgcn_sched_barrier(0);
    __builtin_amdgcn_s_barrier();
  }

#pragma unroll
  for(int mf=0;mf<4;mf++)
#pragma unroll
    for(int nf=0;nf<4;nf++){
      const int col = n0 + wn*64 + nf*16 + ln;
#pragma unroll
      for(int i=0;i<4;i++){
        const int row = m0 + wm*64 + mf*16 + quad*4 + i;
        unsafeAtomicAdd(outa + (size_t)row*256 + col, acc[mf][nf][i]);
      }
    }
}

// ---------------- BN stats: per-channel sum/sumsq over M=16384 ----------------
__global__ void k_stats(const float* __restrict__ acc, float* __restrict__ sum,
                        float* __restrict__ sq){
  const int m0 = blockIdx.x*64;
  const int c = threadIdx.x;
  float s = 0.f, q = 0.f;
  for(int i=0;i<64;i++){
    float v = acc[(size_t)(m0+i)*256 + c];
    s += v; q += v*v;
  }
  unsafeAtomicAdd(sum + c, s);
  unsafeAtomicAdd(sq + c, q);
}

// ---------------- BN1 + ReLU -> padded bf16 NHWC ----------------
__global__ void k_bn1(const float* __restrict__ acc, const float* __restrict__ sum,
                      const float* __restrict__ sq, const float* __restrict__ g,
                      const float* __restrict__ bt, u16* __restrict__ o){
  __shared__ float sc[256], sh[256];
  const int t = threadIdx.x;
  {
    float mean = sum[t] * (1.f/16384.f);
    float var  = sq[t] * (1.f/16384.f) - mean*mean;
    float rstd = rsqrtf(var + 1e-5f);
    float s = g[t] * rstd;
    sc[t] = s; sh[t] = bt[t] - mean*s;
  }
  __syncthreads();
  const int c4 = (t & 63) * 4;
  const float s0 = sc[c4], s1 = sc[c4+1], s2 = sc[c4+2], s3 = sc[c4+3];
  const float h0 = sh[c4], h1 = sh[c4+1], h2 = sh[c4+2], h3 = sh[c4+3];
#pragma unroll
  for(int k=0;k<4;k++){
    int m = blockIdx.x*16 + k*4 + (t>>6);
    int b = m >> 12, hh = (m >> 6) & 63, ww = m & 63;
    const float4 v = *(const float4*)(acc + (size_t)m*256 + c4);
    unsigned int lo = (unsigned int)(u16)f2bf(fmaxf(0.f, v.x*s0 + h0))
                    | ((unsigned int)(u16)f2bf(fmaxf(0.f, v.y*s1 + h1)) << 16);
    unsigned int hi = (unsigned int)(u16)f2bf(fmaxf(0.f, v.z*s2 + h2))
                    | ((unsigned int)(u16)f2bf(fmaxf(0.f, v.w*s3 + h3)) << 16);
    uint2 pr; pr.x = lo; pr.y = hi;
    *(uint2*)(o + ((size_t)(b*66 + hh+1)*66 + ww+1)*256 + c4) = pr;
  }
}

// ---------------- BN2 + ReLU + NHWC->NCHW fp32 output ----------------
__global__ void k_bn2_out(const float* __restrict__ acc, const float* __restrict__ sum,
                          const float* __restrict__ sq, const float* __restrict__ g,
                          const float* __restrict__ bt, float* __restrict__ out){
  __shared__ float tile[64][65];
  __shared__ float sc[64], sh[64];
  const int t = threadIdx.x;
  const int b = blockIdx.z, c0 = blockIdx.y*64, hw0 = blockIdx.x*64;
  if(t < 64){
    int c = c0 + t;
    float mean = sum[c] * (1.f/16384.f);
    float var  = sq[c] * (1.f/16384.f) - mean*mean;
    float rstd = rsqrtf(var + 1e-5f);
    float s = g[c] * rstd;
    sc[t] = s; sh[t] = bt[c] - mean*s;
  }
  __syncthreads();
#pragma unroll
  for(int k=0;k<16;k++){
    int idx = t + k*256;
    int wl = idx >> 6, cl = idx & 63;
    float v = acc[(size_t)((b<<12) + hw0 + wl)*256 + c0 + cl];
    tile[wl][cl] = fmaxf(0.f, v*sc[cl] + sh[cl]);
  }
  __syncthreads();
#pragma unroll
  for(int k=0;k<16;k++){
    int idx = t + k*256;
    int cl = idx >> 6, wl = idx & 63;
    out[(size_t)(b*256 + c0 + cl)*4096 + hw0 + wl] = tile[wl][cl];
  }
}

extern "C" void kernel_launch(void* const* d_in, const int* in_sizes, int n_in,
                              void* d_out, int out_size, void* d_ws, size_t ws_size,
                              hipStream_t stream){
  const float* in_v  = (const float*)d_in[0];
  const float* in_i  = (const float*)d_in[1];
  const float* w_off = (const float*)d_in[2];
  const float* b_off = (const float*)d_in[3];
  const float* w_dcn = (const float*)d_in[4];
  const float* g1    = (const float*)d_in[5];
  const float* bt1   = (const float*)d_in[6];
  const float* w2    = (const float*)d_in[7];
  const float* g2    = (const float*)d_in[8];
  const float* bt2   = (const float*)d_in[9];
  float* out = (float*)d_out;
  char* ws = (char*)d_ws;

  float* off_acc   = (float*)(ws + OFF_ACC_B);
  float* stats     = (float*)(ws + STATS_B);
  float* out1_acc  = (float*)(ws + OUT1_ACC_B);
  float* out2_acc  = (float*)(ws + OUT2_ACC_B);
  u16*   xn_pad    = (u16*)  (ws + XN_PAD_B);
  u16*   out1n_pad = (u16*)  (ws + OUT1N_PAD_B);
  u16*   wofft     = (u16*)  (ws + WOFFT_B);
  u16*   wdcnt     = (u16*)  (ws + WDCNT_B);
  u16*   w2t       = (u16*)  (ws + W2T_B);
  int*   pofs      = (int*)  (ws + POFS_B);
  float* pwgt      = (float*)(ws + PWGT_B);
  float* sum1 = stats,       *sq1 = stats + 256;
  float* sum2 = stats + 512, *sq2 = stats + 768;

  hipMemsetAsync(ws, 0, ZERO_BYTES, stream);
  k_x_to_nhwc<<<dim3(64,8,4), 256, 0, stream>>>(in_v, in_i, xn_pad);
  k_prep_woff<<<576, 256, 0, stream>>>(w_off, wofft);
  k_prep_wdcn<<<4608, 256, 0, stream>>>(w_dcn, wdcnt);
  k_prep_w2<<<2304, 256, 0, stream>>>(w2, w2t);
  k_conv_off<<<dim3(128,4), 256, 0, stream>>>(xn_pad, wofft, off_acc);
  k_prep_off2<<<576, 256, 0, stream>>>(off_acc, b_off, pofs, pwgt);
  k_dcn_pc<<<256, 512, 0, stream>>>(xn_pad, wdcnt, pofs, pwgt, out1_acc);
  k_stats<<<256, 256, 0, stream>>>(out1_acc, sum1, sq1);
  k_bn1<<<1024, 256, 0, stream>>>(out1_acc, sum1, sq1, g1, bt1, out1n_pad);
  k_gemm2<<<dim3(128,2,2), 256, 0, stream>>>(out1n_pad, w2t, out2_acc);
  k_stats<<<256, 256, 0, stream>>>(out2_acc, sum2, sq2);
  k_bn2_out<<<dim3(64,4,4), 256, 0, stream>>>(out2_acc, sum2, sq2, g2, bt2, out);
}

// Round 10
// 370.389 us; speedup vs baseline: 1.1562x; 1.0161x over previous
//
#include <hip/hip_runtime.h>
#include <cstdint>
#include <cstddef>

typedef unsigned short u16;
typedef __attribute__((ext_vector_type(8))) short s16x8;
typedef __attribute__((ext_vector_type(4))) float f32x4;

#define DEV __device__ __forceinline__

DEV float bf2f(short u){
  union { unsigned int i; float f; } v;
  v.i = ((unsigned int)(u16)u) << 16;
  return v.f;
}
DEV short f2bf(float f){
  union { float f; unsigned int i; } v; v.f = f;
  unsigned int u = v.i;
  u += 0x7fffu + ((u >> 16) & 1u);   // RNE
  return (short)(u >> 16);
}
DEV f32x4 f32x4_zero(){
  f32x4 z;
#pragma unroll
  for(int j=0;j<4;j++) z[j]=0.f;
  return z;
}
DEV f32x4 mfma16(s16x8 a, s16x8 b, f32x4 c){
  return __builtin_amdgcn_mfma_f32_16x16x32_bf16(a, b, c, 0, 0, 0);
}
DEV void bar_lds(){
  asm volatile("s_waitcnt lgkmcnt(0)" ::: "memory");
  __builtin_amdgcn_s_barrier();
}
// async global -> LDS, 16 B per lane; per-lane global src, lds dst = base + lane*16
DEV void gload16(const u16* g, u16* l){
  __builtin_amdgcn_global_load_lds(
      (const __attribute__((address_space(1))) unsigned int*)g,
      (__attribute__((address_space(3))) unsigned int*)l, 16, 0, 0);
}

// ---------------- problem constants ----------------
// B=4, Cin=512 (concat), H=W=64, P=9 taps, Cout=256, M = B*H*W = 16384
// Y-formulation: Y[pp, p*256+o] = xn_pad[pp] . W_p  (+ 288 off-conv cols)
// Padded pixel domain: 4*66*66 = 17424 rows, padded to 17536 = 137*128.
// N = 2304 (dcn) + 288 (off, 27 used) -> padded to 2688 = 21*128.
static constexpr size_t STATS_B     = 0;                        // float[1024]
static constexpr size_t OUT2_ACC_B  = 4096;                     // float[16384*256]
static constexpr size_t XN_PAD_B    = 16781312;                 // u16[17536*512]
static constexpr size_t OUT1N_PAD_B = 34738176;                 // u16[4*66*66*256]
static constexpr size_t ZERO_BYTES  = 43659264;
static constexpr size_t OUT1_ACC_B  = 43659264;                 // float[16384*256] (fully written)
static constexpr size_t PPIX_B      = 60436480;                 // int[16384*9*4]
static constexpr size_t PWGT_B      = 62795776;                 // float[16384*9*4]
static constexpr size_t Y_B         = 65155072;                 // u16[17536*2688]
static constexpr size_t WALL_B      = 159428608;                // u16[2688*512]
static constexpr size_t W2T_B       = 162181120;                // u16[256*2304]
// end ~163.4 MB

// ---------------- NCHW fp32 (concat) -> padded NHWC bf16 ----------------
__global__ void k_x_to_nhwc(const float* __restrict__ v, const float* __restrict__ vi,
                            u16* __restrict__ xn){
  __shared__ float tile[64][65];
  const int b = blockIdx.z, c0 = blockIdx.y*64, hw0 = blockIdx.x*64;
  const int h = hw0 >> 6;
  const float* src = (c0 < 256) ? (v  + ((size_t)b*256 + c0)      *4096)
                                : (vi + ((size_t)b*256 + (c0-256))*4096);
  const int t = threadIdx.x;
#pragma unroll
  for(int k=0;k<16;k++){
    int idx = t + k*256;
    int cl = idx >> 6, wl = idx & 63;
    tile[cl][wl] = src[(size_t)cl*4096 + hw0 + wl];
  }
  __syncthreads();
#pragma unroll
  for(int k=0;k<16;k++){
    int idx = t + k*256;
    int wl = idx >> 6, cl = idx & 63;
    xn[((size_t)(b*66 + h+1)*66 + wl+1)*512 + c0 + cl] = (u16)f2bf(tile[cl][wl]);
  }
}

// ---------------- combined weight repack: [2688][512] bf16 ----------------
// n < 2304: p = n>>8, o = n&255 -> w_dcn[o][c][p];  2304..2592: off conv (27 of 32/tap)
__global__ void k_prep_wall(const float* __restrict__ wdcn, const float* __restrict__ woff,
                            u16* __restrict__ wt){
  int idx = blockIdx.x*256 + threadIdx.x;
  if(idx >= 2688*512) return;
  int n = idx >> 9, c = idx & 511;
  float val = 0.f;
  if(n < 2304){
    int p = n >> 8, o = n & 255;
    val = wdcn[(size_t)(o*512 + c)*9 + p];
  } else if(n < 2592){
    int q = n - 2304, p = q >> 5, nn = q & 31;
    if(nn < 27) val = woff[(size_t)(nn*512 + c)*9 + p];
  }
  wt[idx] = (u16)f2bf(val);
}
__global__ void k_prep_w2(const float* __restrict__ w, u16* __restrict__ wt){
  int idx = blockIdx.x*256 + threadIdx.x;
  if(idx >= 256*2304) return;
  int n = idx / 2304, k = idx % 2304;
  int t = k >> 8, c = k & 255;
  wt[idx] = (u16)f2bf(w[(size_t)(n*256 + c)*9 + t]);
}

// ---------------- dense GEMM: Y[17536][2688] = xn_pad[17536][512] x Wall^T ----------------
// 128x128 tile, BK=64, dbuf LDS, counted vmcnt(8). grid (137, 21) = 2877 blocks.
__global__ __launch_bounds__(256, 2) void k_gemm_big(
    const u16* __restrict__ A, const u16* __restrict__ wt, u16* __restrict__ Y){
  __shared__ short A_lds[2][8][128][8];   // 32 KB
  __shared__ short B_lds[2][8][128][8];   // 32 KB
  const int tid = threadIdx.x;
  const int lane = tid & 63, wid = tid >> 6;
  const int quad = lane >> 4, ln = lane & 15;
  const int wm = wid >> 1, wn = wid & 1;
  const int m0 = blockIdx.x * 128;
  const int n0 = blockIdx.y * 128;
  constexpr int NPH = 8;                  // K=512 / 64
  f32x4 acc[4][4];
#pragma unroll
  for(int mf=0;mf<4;mf++)
#pragma unroll
    for(int nf=0;nf<4;nf++) acc[mf][nf] = f32x4_zero();

  auto stage = [&](int t, int bi){        // 8 gload16 per wave (4 A + 4 B)
    const int k0 = t*64;
#pragma unroll
    for(int i=0;i<4;i++){
      const int idx = wid*4 + i;          // 0..15
      const int s = idx >> 1, rh = (idx & 1)*64;
      gload16(A  + (size_t)(m0 + rh + lane)*512 + k0 + s*8, (u16*)&A_lds[bi][s][rh][0]);
      gload16(wt + (size_t)(n0 + rh + lane)*512 + k0 + s*8, (u16*)&B_lds[bi][s][rh][0]);
    }
  };
  auto compute = [&](int bi){             // 32 MFMA per wave
#pragma unroll
    for(int kk=0;kk<2;kk++){
      s16x8 af[4], bf[4];
#pragma unroll
      for(int mf=0;mf<4;mf++)
        af[mf] = *(const s16x8*)&A_lds[bi][kk*4+quad][wm*64 + mf*16 + ln][0];
#pragma unroll
      for(int nf=0;nf<4;nf++)
        bf[nf] = *(const s16x8*)&B_lds[bi][kk*4+quad][wn*64 + nf*16 + ln][0];
#pragma unroll
      for(int mf=0;mf<4;mf++)
#pragma unroll
        for(int nf=0;nf<4;nf++)
          acc[mf][nf] = mfma16(af[mf], bf[nf], acc[mf][nf]);
    }
  };

  stage(0, 0);
  asm volatile("s_waitcnt vmcnt(0)" ::: "memory");
  __builtin_amdgcn_s_barrier();
  stage(1, 1);
  for(int t = 0; t < NPH; ++t){
    const int bi = t & 1;
    compute(bi);
    bar_lds();
    if(t + 2 < NPH){
      stage(t + 2, bi);
      asm volatile("s_waitcnt vmcnt(8)" ::: "memory");
    } else {
      asm volatile("s_waitcnt vmcnt(0)" ::: "memory");
    }
    __builtin_amdgcn_sched_barrier(0);
    __builtin_amdgcn_s_barrier();
  }

#pragma unroll
  for(int mf=0;mf<4;mf++)
#pragma unroll
    for(int nf=0;nf<4;nf++){
      const int col = n0 + wn*64 + nf*16 + ln;
#pragma unroll
      for(int i=0;i<4;i++){
        const int row = m0 + wm*64 + mf*16 + quad*4 + i;
        Y[(size_t)row*2688 + col] = (u16)f2bf(acc[mf][nf][i]);
      }
    }
}

// ---------------- off-combine: 9-tap shifted sum of Y off-cols -> bilinear tables -------
// grid 256 (one (b,h) row), 256 threads.
__global__ __launch_bounds__(256) void k_off_combine(
    const u16* __restrict__ Y, const float* __restrict__ boff,
    int* __restrict__ ppix, float* __restrict__ pwgt){
  __shared__ float offs[64][32];
  const int t = threadIdx.x;
  const int b = blockIdx.x >> 6, h = blockIdx.x & 63;
  const int w = t >> 2, g = t & 3;
  float acc[8];
#pragma unroll
  for(int j=0;j<8;j++) acc[j] = 0.f;
  for(int p=0;p<9;p++){
    const int pp = (b*66 + h + p/3)*66 + (w + p%3);   // fixed 3x3 taps, padded coords
    s16x8 v = *(const s16x8*)(Y + (size_t)pp*2688 + 2304 + p*32 + g*8);
#pragma unroll
    for(int j=0;j<8;j++) acc[j] += bf2f(v[j]);
  }
#pragma unroll
  for(int j=0;j<8;j++) offs[w][g*8 + j] = acc[j];
  __syncthreads();
  for(int id = t; id < 576; id += 256){
    const int tp = id / 64, ww = id & 63;
    const int m = (b<<12) + (h<<6) + ww;
    float dy = offs[ww][2*tp]   + boff[2*tp];
    float dx = offs[ww][2*tp+1] + boff[2*tp+1];
    float mz = offs[ww][18+tp]  + boff[18+tp];
    float mk = 1.f / (1.f + expf(-mz));
    float ypos = (float)(h - 1 + tp/3) + dy;
    float xpos = (float)(ww - 1 + tp%3) + dx;
    float y0f = floorf(ypos), x0f = floorf(xpos);
    float ly = ypos - y0f, lx = xpos - x0f;
    int y0 = (int)y0f, x0 = (int)x0f;
    const int id4 = (m*9 + tp)*4;
#pragma unroll
    for(int k=0;k<4;k++){
      int ddy = k >> 1, ddx = k & 1;
      int yi = y0 + ddy, xi = x0 + ddx;
      // clamp into padded domain; border rows of Y are exact zeros
      int yc = yi < -1 ? -1 : (yi > 64 ? 64 : yi);
      int xc = xi < -1 ? -1 : (xi > 64 ? 64 : xi);
      float wk = (ddy ? ly : 1.f-ly) * (ddx ? lx : 1.f-lx) * mk;
      ppix[id4+k] = (b*66 + yc+1)*66 + xc+1;          // padded pixel index
      pwgt[id4+k] = wk;
    }
  }
}

// ---------------- bilinear combine: out1[m] = sum_{p,k} wgt * Y[nbr, p*256:+256] --------
// grid 256 (one (b,h) row), 512 threads = 8 waves x 8 pixels; lane owns 4 cols.
__global__ __launch_bounds__(512) void k_combine(
    const u16* __restrict__ Y, const int* __restrict__ ppix,
    const float* __restrict__ pwgt, float* __restrict__ out1){
  __shared__ int   s_pp[64][9][4];
  __shared__ float s_wg[64][9][4];
  const int t = threadIdx.x;
  const int b = blockIdx.x >> 6, h = blockIdx.x & 63;
  const int m_row = (b<<12) + (h<<6);
  for(int id = t; id < 576; id += 512){
    const int mo = id / 9, tp = id - mo*9;
    const size_t i4 = ((size_t)(m_row + mo)*9 + tp)*4;
    int4   pp4 = *(const int4*)  (ppix + i4);
    float4 wg4 = *(const float4*)(pwgt + i4);
    s_pp[mo][tp][0] = pp4.x; s_pp[mo][tp][1] = pp4.y;
    s_pp[mo][tp][2] = pp4.z; s_pp[mo][tp][3] = pp4.w;
    s_wg[mo][tp][0] = wg4.x; s_wg[mo][tp][1] = wg4.y;
    s_wg[mo][tp][2] = wg4.z; s_wg[mo][tp][3] = wg4.w;
  }
  __syncthreads();
  const int wv = t >> 6, lane = t & 63;
  const int c0 = lane*4;
  const int pw0 = wv*8;
  float acc[8][4];
#pragma unroll
  for(int pw=0;pw<8;pw++)
#pragma unroll
    for(int j=0;j<4;j++) acc[pw][j] = 0.f;

  for(int tp = 0; tp < 9; ++tp){
    const int cb = tp*256 + c0;
#pragma unroll
    for(int pw=0;pw<8;pw++){
      const int px = pw0 + pw;
#pragma unroll
      for(int k=0;k<4;k++){
        const float wk = s_wg[px][tp][k];
        const int   pp = s_pp[px][tp][k];
        ushort4 v = *(const ushort4*)(Y + (size_t)pp*2688 + cb);
        acc[pw][0] = fmaf(wk, bf2f((short)v.x), acc[pw][0]);
        acc[pw][1] = fmaf(wk, bf2f((short)v.y), acc[pw][1]);
        acc[pw][2] = fmaf(wk, bf2f((short)v.z), acc[pw][2]);
        acc[pw][3] = fmaf(wk, bf2f((short)v.w), acc[pw][3]);
      }
    }
  }
#pragma unroll
  for(int pw=0;pw<8;pw++){
    float4 o4;
    o4.x = acc[pw][0]; o4.y = acc[pw][1]; o4.z = acc[pw][2]; o4.w = acc[pw][3];
    *(float4*)(out1 + (size_t)(m_row + pw0 + pw)*256 + c0) = o4;
  }
}

// ---------------- GEMM2: out2 = im2col(out1n_pad)[16384][2304] x W2T[256][2304]^T ------
__global__ __launch_bounds__(256, 2) void k_gemm2(
    const u16* __restrict__ a_pad, const u16* __restrict__ wt, float* __restrict__ outa){
  __shared__ short A_lds[2][8][128][8];   // 32 KB
  __shared__ short B_lds[2][8][128][8];   // 32 KB
  const int tid = threadIdx.x;
  const int lane = tid & 63, wid = tid >> 6;
  const int quad = lane >> 4, ln = lane & 15;
  const int wm = wid >> 1, wn = wid & 1;
  const int m0 = blockIdx.x * 128;
  const int n0 = blockIdx.y * 128;
  const int kbase = blockIdx.z * 1152;
  const int b = m0 >> 12;
  const int h0 = (m0 & 4095) >> 6;
  constexpr int NPH = 18;
  f32x4 acc[4][4];
#pragma unroll
  for(int mf=0;mf<4;mf++)
#pragma unroll
    for(int nf=0;nf<4;nf++) acc[mf][nf] = f32x4_zero();

  auto stage = [&](int t, int bi){
    const int k0 = kbase + t*64;
    const int tp = k0 >> 8, cit = k0 & 255;
    const int ty = tp/3, tx = tp - ty*3;
#pragma unroll
    for(int i=0;i<4;i++){
      const int idx = wid*4 + i;
      const int s = idx >> 1, rh = (idx & 1)*64;
      const int hh = h0 + (rh >> 6) + ty;
      gload16(a_pad + ((size_t)(b*66 + hh)*66 + lane + tx)*256 + cit + s*8,
              (u16*)&A_lds[bi][s][rh][0]);
      gload16(wt + (size_t)(n0 + rh + lane)*2304 + k0 + s*8,
              (u16*)&B_lds[bi][s][rh][0]);
    }
  };
  auto compute = [&](int bi){
#pragma unroll
    for(int kk=0;kk<2;kk++){
      s16x8 af[4], bf[4];
#pragma unroll
      for(int mf=0;mf<4;mf++)
        af[mf] = *(const s16x8*)&A_lds[bi][kk*4+quad][wm*64 + mf*16 + ln][0];
#pragma unroll
      for(int nf=0;nf<4;nf++)
        bf[nf] = *(const s16x8*)&B_lds[bi][kk*4+quad][wn*64 + nf*16 + ln][0];
#pragma unroll
      for(int mf=0;mf<4;mf++)
#pragma unroll
        for(int nf=0;nf<4;nf++)
          acc[mf][nf] = mfma16(af[mf], bf[nf], acc[mf][nf]);
    }
  };

  stage(0, 0);
  asm volatile("s_waitcnt vmcnt(0)" ::: "memory");
  __builtin_amdgcn_s_barrier();
  stage(1, 1);
  for(int t = 0; t < NPH; ++t){
    const int bi = t & 1;
    compute(bi);
    bar_lds();
    if(t + 2 < NPH){
      stage(t + 2, bi);
      asm volatile("s_waitcnt vmcnt(8)" ::: "memory");
    } else {
      asm volatile("s_waitcnt vmcnt(0)" ::: "memory");
    }
    __builtin_amdgcn_sched_barrier(0);
    __builtin_amdgcn_s_barrier();
  }

#pragma unroll
  for(int mf=0;mf<4;mf++)
#pragma unroll
    for(int nf=0;nf<4;nf++){
      const int col = n0 + wn*64 + nf*16 + ln;
#pragma unroll
      for(int i=0;i<4;i++){
        const int row = m0 + wm*64 + mf*16 + quad*4 + i;
        unsafeAtomicAdd(outa + (size_t)row*256 + col, acc[mf][nf][i]);
      }
    }
}

// ---------------- BN stats: per-channel sum/sumsq over M=16384 ----------------
__global__ void k_stats(const float* __restrict__ acc, float* __restrict__ sum,
                        float* __restrict__ sq){
  const int m0 = blockIdx.x*64;
  const int c = threadIdx.x;
  float s = 0.f, q = 0.f;
  for(int i=0;i<64;i++){
    float v = acc[(size_t)(m0+i)*256 + c];
    s += v; q += v*v;
  }
  unsafeAtomicAdd(sum + c, s);
  unsafeAtomicAdd(sq + c, q);
}

// ---------------- BN1 + ReLU -> padded bf16 NHWC ----------------
__global__ void k_bn1(const float* __restrict__ acc, const float* __restrict__ sum,
                      const float* __restrict__ sq, const float* __restrict__ g,
                      const float* __restrict__ bt, u16* __restrict__ o){
  __shared__ float sc[256], sh[256];
  const int t = threadIdx.x;
  {
    float mean = sum[t] * (1.f/16384.f);
    float var  = sq[t] * (1.f/16384.f) - mean*mean;
    float rstd = rsqrtf(var + 1e-5f);
    float s = g[t] * rstd;
    sc[t] = s; sh[t] = bt[t] - mean*s;
  }
  __syncthreads();
  const int c4 = (t & 63) * 4;
  const float s0 = sc[c4], s1 = sc[c4+1], s2 = sc[c4+2], s3 = sc[c4+3];
  const float h0 = sh[c4], h1 = sh[c4+1], h2 = sh[c4+2], h3 = sh[c4+3];
#pragma unroll
  for(int k=0;k<4;k++){
    int m = blockIdx.x*16 + k*4 + (t>>6);
    int b = m >> 12, hh = (m >> 6) & 63, ww = m & 63;
    const float4 v = *(const float4*)(acc + (size_t)m*256 + c4);
    unsigned int lo = (unsigned int)(u16)f2bf(fmaxf(0.f, v.x*s0 + h0))
                    | ((unsigned int)(u16)f2bf(fmaxf(0.f, v.y*s1 + h1)) << 16);
    unsigned int hi = (unsigned int)(u16)f2bf(fmaxf(0.f, v.z*s2 + h2))
                    | ((unsigned int)(u16)f2bf(fmaxf(0.f, v.w*s3 + h3)) << 16);
    uint2 pr; pr.x = lo; pr.y = hi;
    *(uint2*)(o + ((size_t)(b*66 + hh+1)*66 + ww+1)*256 + c4) = pr;
  }
}

// ---------------- BN2 + ReLU + NHWC->NCHW fp32 output ----------------
__global__ void k_bn2_out(const float* __restrict__ acc, const float* __restrict__ sum,
                          const float* __restrict__ sq, const float* __restrict__ g,
                          const float* __restrict__ bt, float* __restrict__ out){
  __shared__ float tile[64][65];
  __shared__ float sc[64], sh[64];
  const int t = threadIdx.x;
  const int b = blockIdx.z, c0 = blockIdx.y*64, hw0 = blockIdx.x*64;
  if(t < 64){
    int c = c0 + t;
    float mean = sum[c] * (1.f/16384.f);
    float var  = sq[c] * (1.f/16384.f) - mean*mean;
    float rstd = rsqrtf(var + 1e-5f);
    float s = g[c] * rstd;
    sc[t] = s; sh[t] = bt[c] - mean*s;
  }
  __syncthreads();
#pragma unroll
  for(int k=0;k<16;k++){
    int idx = t + k*256;
    int wl = idx >> 6, cl = idx & 63;
    float v = acc[(size_t)((b<<12) + hw0 + wl)*256 + c0 + cl];
    tile[wl][cl] = fmaxf(0.f, v*sc[cl] + sh[cl]);
  }
  __syncthreads();
#pragma unroll
  for(int k=0;k<16;k++){
    int idx = t + k*256;
    int cl = idx >> 6, wl = idx & 63;
    out[(size_t)(b*256 + c0 + cl)*4096 + hw0 + wl] = tile[wl][cl];
  }
}

extern "C" void kernel_launch(void* const* d_in, const int* in_sizes, int n_in,
                              void* d_out, int out_size, void* d_ws, size_t ws_size,
                              hipStream_t stream){
  const float* in_v  = (const float*)d_in[0];
  const float* in_i  = (const float*)d_in[1];
  const float* w_off = (const float*)d_in[2];
  const float* b_off = (const float*)d_in[3];
  const float* w_dcn = (const float*)d_in[4];
  const float* g1    = (const float*)d_in[5];
  const float* bt1   = (const float*)d_in[6];
  const float* w2    = (const float*)d_in[7];
  const float* g2    = (const float*)d_in[8];
  const float* bt2   = (const float*)d_in[9];
  float* out = (float*)d_out;
  char* ws = (char*)d_ws;

  float* stats     = (float*)(ws + STATS_B);
  float* out2_acc  = (float*)(ws + OUT2_ACC_B);
  u16*   xn_pad    = (u16*)  (ws + XN_PAD_B);
  u16*   out1n_pad = (u16*)  (ws + OUT1N_PAD_B);
  float* out1_acc  = (float*)(ws + OUT1_ACC_B);
  int*   ppix      = (int*)  (ws + PPIX_B);
  float* pwgt      = (float*)(ws + PWGT_B);
  u16*   Ymat      = (u16*)  (ws + Y_B);
  u16*   wall      = (u16*)  (ws + WALL_B);
  u16*   w2t       = (u16*)  (ws + W2T_B);
  float* sum1 = stats,       *sq1 = stats + 256;
  float* sum2 = stats + 512, *sq2 = stats + 768;

  hipMemsetAsync(ws, 0, ZERO_BYTES, stream);
  k_x_to_nhwc<<<dim3(64,8,4), 256, 0, stream>>>(in_v, in_i, xn_pad);
  k_prep_wall<<<5376, 256, 0, stream>>>(w_dcn, w_off, wall);
  k_prep_w2<<<2304, 256, 0, stream>>>(w2, w2t);
  k_gemm_big<<<dim3(137,21), 256, 0, stream>>>(xn_pad, wall, Ymat);
  k_off_combine<<<256, 256, 0, stream>>>(Ymat, b_off, ppix, pwgt);
  k_combine<<<256, 512, 0, stream>>>(Ymat, ppix, pwgt, out1_acc);
  k_stats<<<256, 256, 0, stream>>>(out1_acc, sum1, sq1);
  k_bn1<<<1024, 256, 0, stream>>>(out1_acc, sum1, sq1, g1, bt1, out1n_pad);
  k_gemm2<<<dim3(128,2,2), 256, 0, stream>>>(out1n_pad, w2t, out2_acc);
  k_stats<<<256, 256, 0, stream>>>(out2_acc, sum2, sq2);
  k_bn2_out<<<dim3(64,4,4), 256, 0, stream>>>(out2_acc, sum2, sq2, g2, bt2, out);
}

// Round 11
// 359.210 us; speedup vs baseline: 1.1922x; 1.0311x over previous
//
#include <hip/hip_runtime.h>
#include <cstdint>
#include <cstddef>

typedef unsigned short u16;
typedef __attribute__((ext_vector_type(8))) short s16x8;
typedef __attribute__((ext_vector_type(4))) float f32x4;

#define DEV __device__ __forceinline__

DEV float bf2f(short u){
  union { unsigned int i; float f; } v;
  v.i = ((unsigned int)(u16)u) << 16;
  return v.f;
}
DEV short f2bf(float f){
  union { float f; unsigned int i; } v; v.f = f;
  unsigned int u = v.i;
  u += 0x7fffu + ((u >> 16) & 1u);   // RNE
  return (short)(u >> 16);
}
DEV f32x4 f32x4_zero(){
  f32x4 z;
#pragma unroll
  for(int j=0;j<4;j++) z[j]=0.f;
  return z;
}
DEV f32x4 mfma16(s16x8 a, s16x8 b, f32x4 c){
  return __builtin_amdgcn_mfma_f32_16x16x32_bf16(a, b, c, 0, 0, 0);
}
DEV void bar_lds(){
  asm volatile("s_waitcnt lgkmcnt(0)" ::: "memory");
  __builtin_amdgcn_s_barrier();
}
// async global -> LDS, 16 B per lane; per-lane global src, lds dst = base + lane*16
DEV void gload16(const u16* g, u16* l){
  __builtin_amdgcn_global_load_lds(
      (const __attribute__((address_space(1))) unsigned int*)g,
      (__attribute__((address_space(3))) unsigned int*)l, 16, 0, 0);
}

// ---------------- problem constants ----------------
// B=4, Cin=512 (concat), H=W=64, P=9 taps, Cout=256, M = B*H*W = 16384
// Y-formulation: Y[pp, p*256+o] = xn_pad[pp] . W_p  (+ 288 off-conv cols)
// Padded pixel domain: 4*66*66 = 17424 rows, padded to 17536 = 137*128.
// N = 2304 (dcn) + 288 (off, 27 used) -> padded to 2688 = 21*128.
static constexpr size_t STATS_B     = 0;                        // float[1024]
static constexpr size_t OUT2_ACC_B  = 4096;                     // float[16384*256]
static constexpr size_t XN_PAD_B    = 16781312;                 // u16[17536*512]
static constexpr size_t OUT1N_PAD_B = 34738176;                 // u16[4*66*66*256]
static constexpr size_t ZERO_BYTES  = 43659264;
static constexpr size_t OUT1_ACC_B  = 43659264;                 // float[16384*256] (fully written)
static constexpr size_t PPIX_B      = 60436480;                 // int[16384*9*4]
static constexpr size_t PWGT_B      = 62795776;                 // float[16384*9*4]
static constexpr size_t Y_B         = 65155072;                 // u16[17536*2688]
static constexpr size_t WALL_B      = 159428608;                // u16[2688*512]
static constexpr size_t W2T_B       = 162181120;                // u16[256*2304]
// end ~163.4 MB

// ---------------- NCHW fp32 (concat) -> padded NHWC bf16 ----------------
__global__ void k_x_to_nhwc(const float* __restrict__ v, const float* __restrict__ vi,
                            u16* __restrict__ xn){
  __shared__ float tile[64][65];
  const int b = blockIdx.z, c0 = blockIdx.y*64, hw0 = blockIdx.x*64;
  const int h = hw0 >> 6;
  const float* src = (c0 < 256) ? (v  + ((size_t)b*256 + c0)      *4096)
                                : (vi + ((size_t)b*256 + (c0-256))*4096);
  const int t = threadIdx.x;
#pragma unroll
  for(int k=0;k<16;k++){
    int idx = t + k*256;
    int cl = idx >> 6, wl = idx & 63;
    tile[cl][wl] = src[(size_t)cl*4096 + hw0 + wl];
  }
  __syncthreads();
#pragma unroll
  for(int k=0;k<16;k++){
    int idx = t + k*256;
    int wl = idx >> 6, cl = idx & 63;
    xn[((size_t)(b*66 + h+1)*66 + wl+1)*512 + c0 + cl] = (u16)f2bf(tile[cl][wl]);
  }
}

// ---------------- combined weight repack: [2688][512] bf16 ----------------
// n < 2304: p = n>>8, o = n&255 -> w_dcn[o][c][p];  2304..2592: off conv (27 of 32/tap)
__global__ void k_prep_wall(const float* __restrict__ wdcn, const float* __restrict__ woff,
                            u16* __restrict__ wt){
  int idx = blockIdx.x*256 + threadIdx.x;
  if(idx >= 2688*512) return;
  int n = idx >> 9, c = idx & 511;
  float val = 0.f;
  if(n < 2304){
    int p = n >> 8, o = n & 255;
    val = wdcn[(size_t)(o*512 + c)*9 + p];
  } else if(n < 2592){
    int q = n - 2304, p = q >> 5, nn = q & 31;
    if(nn < 27) val = woff[(size_t)(nn*512 + c)*9 + p];
  }
  wt[idx] = (u16)f2bf(val);
}
__global__ void k_prep_w2(const float* __restrict__ w, u16* __restrict__ wt){
  int idx = blockIdx.x*256 + threadIdx.x;
  if(idx >= 256*2304) return;
  int n = idx / 2304, k = idx % 2304;
  int t = k >> 8, c = k & 255;
  wt[idx] = (u16)f2bf(w[(size_t)(n*256 + c)*9 + t]);
}

// ---------------- dense GEMM: Y[17536][2688] = xn_pad[17536][512] x Wall^T ----------------
// 128x128 tile, BK=64, dbuf LDS, counted vmcnt(8).
// XCD-aware mapping: each XCD owns m-tiles {xcd, xcd+8, ...}; n iterates fastest
// within an m-tile, so A-tile + all B panels stay resident in the XCD's 4MB L2
// (working set ~3MB). Linear grid 8*378=3024, ~5% no-op blocks (mt>=137).
__global__ __launch_bounds__(256, 2) void k_gemm_big(
    const u16* __restrict__ A, const u16* __restrict__ wt, u16* __restrict__ Y){
  const int bid = blockIdx.x;
  const int xcd = bid & 7;
  const int j   = bid >> 3;               // 0..377
  const int mt  = xcd + 8*(j/21);
  const int nt  = j % 21;
  if(mt >= 137) return;
  __shared__ short A_lds[2][8][128][8];   // 32 KB
  __shared__ short B_lds[2][8][128][8];   // 32 KB
  const int tid = threadIdx.x;
  const int lane = tid & 63, wid = tid >> 6;
  const int quad = lane >> 4, ln = lane & 15;
  const int wm = wid >> 1, wn = wid & 1;
  const int m0 = mt * 128;
  const int n0 = nt * 128;
  constexpr int NPH = 8;                  // K=512 / 64
  f32x4 acc[4][4];
#pragma unroll
  for(int mf=0;mf<4;mf++)
#pragma unroll
    for(int nf=0;nf<4;nf++) acc[mf][nf] = f32x4_zero();

  auto stage = [&](int t, int bi){        // 8 gload16 per wave (4 A + 4 B)
    const int k0 = t*64;
#pragma unroll
    for(int i=0;i<4;i++){
      const int idx = wid*4 + i;          // 0..15
      const int s = idx >> 1, rh = (idx & 1)*64;
      gload16(A  + (size_t)(m0 + rh + lane)*512 + k0 + s*8, (u16*)&A_lds[bi][s][rh][0]);
      gload16(wt + (size_t)(n0 + rh + lane)*512 + k0 + s*8, (u16*)&B_lds[bi][s][rh][0]);
    }
  };
  auto compute = [&](int bi){             // 32 MFMA per wave
#pragma unroll
    for(int kk=0;kk<2;kk++){
      s16x8 af[4], bf[4];
#pragma unroll
      for(int mf=0;mf<4;mf++)
        af[mf] = *(const s16x8*)&A_lds[bi][kk*4+quad][wm*64 + mf*16 + ln][0];
#pragma unroll
      for(int nf=0;nf<4;nf++)
        bf[nf] = *(const s16x8*)&B_lds[bi][kk*4+quad][wn*64 + nf*16 + ln][0];
#pragma unroll
      for(int mf=0;mf<4;mf++)
#pragma unroll
        for(int nf=0;nf<4;nf++)
          acc[mf][nf] = mfma16(af[mf], bf[nf], acc[mf][nf]);
    }
  };

  stage(0, 0);
  asm volatile("s_waitcnt vmcnt(0)" ::: "memory");
  __builtin_amdgcn_s_barrier();
  stage(1, 1);
  for(int t = 0; t < NPH; ++t){
    const int bi = t & 1;
    compute(bi);
    bar_lds();
    if(t + 2 < NPH){
      stage(t + 2, bi);
      asm volatile("s_waitcnt vmcnt(8)" ::: "memory");
    } else {
      asm volatile("s_waitcnt vmcnt(0)" ::: "memory");
    }
    __builtin_amdgcn_sched_barrier(0);
    __builtin_amdgcn_s_barrier();
  }

#pragma unroll
  for(int mf=0;mf<4;mf++)
#pragma unroll
    for(int nf=0;nf<4;nf++){
      const int col = n0 + wn*64 + nf*16 + ln;
#pragma unroll
      for(int i=0;i<4;i++){
        const int row = m0 + wm*64 + mf*16 + quad*4 + i;
        Y[(size_t)row*2688 + col] = (u16)f2bf(acc[mf][nf][i]);
      }
    }
}

// ---------------- off-combine: 9-tap shifted sum of Y off-cols -> bilinear tables -------
// grid 256 (one (b,h) row), 256 threads.
__global__ __launch_bounds__(256) void k_off_combine(
    const u16* __restrict__ Y, const float* __restrict__ boff,
    int* __restrict__ ppix, float* __restrict__ pwgt){
  __shared__ float offs[64][32];
  const int t = threadIdx.x;
  const int b = blockIdx.x >> 6, h = blockIdx.x & 63;
  const int w = t >> 2, g = t & 3;
  float acc[8];
#pragma unroll
  for(int j=0;j<8;j++) acc[j] = 0.f;
  for(int p=0;p<9;p++){
    const int pp = (b*66 + h + p/3)*66 + (w + p%3);   // fixed 3x3 taps, padded coords
    s16x8 v = *(const s16x8*)(Y + (size_t)pp*2688 + 2304 + p*32 + g*8);
#pragma unroll
    for(int j=0;j<8;j++) acc[j] += bf2f(v[j]);
  }
#pragma unroll
  for(int j=0;j<8;j++) offs[w][g*8 + j] = acc[j];
  __syncthreads();
  for(int id = t; id < 576; id += 256){
    const int tp = id / 64, ww = id & 63;
    const int m = (b<<12) + (h<<6) + ww;
    float dy = offs[ww][2*tp]   + boff[2*tp];
    float dx = offs[ww][2*tp+1] + boff[2*tp+1];
    float mz = offs[ww][18+tp]  + boff[18+tp];
    float mk = 1.f / (1.f + expf(-mz));
    float ypos = (float)(h - 1 + tp/3) + dy;
    float xpos = (float)(ww - 1 + tp%3) + dx;
    float y0f = floorf(ypos), x0f = floorf(xpos);
    float ly = ypos - y0f, lx = xpos - x0f;
    int y0 = (int)y0f, x0 = (int)x0f;
    const int id4 = (m*9 + tp)*4;
#pragma unroll
    for(int k=0;k<4;k++){
      int ddy = k >> 1, ddx = k & 1;
      int yi = y0 + ddy, xi = x0 + ddx;
      // clamp into padded domain; border rows of Y are exact zeros
      int yc = yi < -1 ? -1 : (yi > 64 ? 64 : yi);
      int xc = xi < -1 ? -1 : (xi > 64 ? 64 : xi);
      float wk = (ddy ? ly : 1.f-ly) * (ddx ? lx : 1.f-lx) * mk;
      ppix[id4+k] = (b*66 + yc+1)*66 + xc+1;          // padded pixel index
      pwgt[id4+k] = wk;
    }
  }
}

// ---------------- bilinear combine: out1[m] = sum_{p,k} wgt * Y[nbr, p*256:+256] --------
// grid 256 (one (b,h) row), 512 threads = 8 waves x 8 pixels; lane owns 4 cols.
__global__ __launch_bounds__(512) void k_combine(
    const u16* __restrict__ Y, const int* __restrict__ ppix,
    const float* __restrict__ pwgt, float* __restrict__ out1){
  __shared__ int   s_pp[64][9][4];
  __shared__ float s_wg[64][9][4];
  const int t = threadIdx.x;
  const int b = blockIdx.x >> 6, h = blockIdx.x & 63;
  const int m_row = (b<<12) + (h<<6);
  for(int id = t; id < 576; id += 512){
    const int mo = id / 9, tp = id - mo*9;
    const size_t i4 = ((size_t)(m_row + mo)*9 + tp)*4;
    int4   pp4 = *(const int4*)  (ppix + i4);
    float4 wg4 = *(const float4*)(pwgt + i4);
    s_pp[mo][tp][0] = pp4.x; s_pp[mo][tp][1] = pp4.y;
    s_pp[mo][tp][2] = pp4.z; s_pp[mo][tp][3] = pp4.w;
    s_wg[mo][tp][0] = wg4.x; s_wg[mo][tp][1] = wg4.y;
    s_wg[mo][tp][2] = wg4.z; s_wg[mo][tp][3] = wg4.w;
  }
  __syncthreads();
  const int wv = t >> 6, lane = t & 63;
  const int c0 = lane*4;
  const int pw0 = wv*8;
  float acc[8][4];
#pragma unroll
  for(int pw=0;pw<8;pw++)
#pragma unroll
    for(int j=0;j<4;j++) acc[pw][j] = 0.f;

  for(int tp = 0; tp < 9; ++tp){
    const int cb = tp*256 + c0;
#pragma unroll
    for(int pw=0;pw<8;pw++){
      const int px = pw0 + pw;
#pragma unroll
      for(int k=0;k<4;k++){
        const float wk = s_wg[px][tp][k];
        const int   pp = s_pp[px][tp][k];
        ushort4 v = *(const ushort4*)(Y + (size_t)pp*2688 + cb);
        acc[pw][0] = fmaf(wk, bf2f((short)v.x), acc[pw][0]);
        acc[pw][1] = fmaf(wk, bf2f((short)v.y), acc[pw][1]);
        acc[pw][2] = fmaf(wk, bf2f((short)v.z), acc[pw][2]);
        acc[pw][3] = fmaf(wk, bf2f((short)v.w), acc[pw][3]);
      }
    }
  }
#pragma unroll
  for(int pw=0;pw<8;pw++){
    float4 o4;
    o4.x = acc[pw][0]; o4.y = acc[pw][1]; o4.z = acc[pw][2]; o4.w = acc[pw][3];
    *(float4*)(out1 + (size_t)(m_row + pw0 + pw)*256 + c0) = o4;
  }
}

// ---------------- GEMM2: out2 = im2col(out1n_pad)[16384][2304] x W2T[256][2304]^T ------
// XCD-aware mapping: linear grid 512; each XCD owns m-tiles {xcd, xcd+8, ...};
// (n,kz) iterate within an m-tile -> per-XCD L2 working set ~2.7MB (was ~9MB thrash).
__global__ __launch_bounds__(256, 2) void k_gemm2(
    const u16* __restrict__ a_pad, const u16* __restrict__ wt, float* __restrict__ outa){
  const int bid = blockIdx.x;
  const int xcd = bid & 7;
  const int j   = bid >> 3;               // 0..63
  const int mt  = xcd + 8*(j >> 2);       // 0..127
  const int rest = j & 3;
  const int nt  = rest & 1;
  const int kz  = rest >> 1;
  __shared__ short A_lds[2][8][128][8];   // 32 KB
  __shared__ short B_lds[2][8][128][8];   // 32 KB
  const int tid = threadIdx.x;
  const int lane = tid & 63, wid = tid >> 6;
  const int quad = lane >> 4, ln = lane & 15;
  const int wm = wid >> 1, wn = wid & 1;
  const int m0 = mt * 128;
  const int n0 = nt * 128;
  const int kbase = kz * 1152;
  const int b = m0 >> 12;
  const int h0 = (m0 & 4095) >> 6;
  constexpr int NPH = 18;
  f32x4 acc[4][4];
#pragma unroll
  for(int mf=0;mf<4;mf++)
#pragma unroll
    for(int nf=0;nf<4;nf++) acc[mf][nf] = f32x4_zero();

  auto stage = [&](int t, int bi){
    const int k0 = kbase + t*64;
    const int tp = k0 >> 8, cit = k0 & 255;
    const int ty = tp/3, tx = tp - ty*3;
#pragma unroll
    for(int i=0;i<4;i++){
      const int idx = wid*4 + i;
      const int s = idx >> 1, rh = (idx & 1)*64;
      const int hh = h0 + (rh >> 6) + ty;
      gload16(a_pad + ((size_t)(b*66 + hh)*66 + lane + tx)*256 + cit + s*8,
              (u16*)&A_lds[bi][s][rh][0]);
      gload16(wt + (size_t)(n0 + rh + lane)*2304 + k0 + s*8,
              (u16*)&B_lds[bi][s][rh][0]);
    }
  };
  auto compute = [&](int bi){
#pragma unroll
    for(int kk=0;kk<2;kk++){
      s16x8 af[4], bf[4];
#pragma unroll
      for(int mf=0;mf<4;mf++)
        af[mf] = *(const s16x8*)&A_lds[bi][kk*4+quad][wm*64 + mf*16 + ln][0];
#pragma unroll
      for(int nf=0;nf<4;nf++)
        bf[nf] = *(const s16x8*)&B_lds[bi][kk*4+quad][wn*64 + nf*16 + ln][0];
#pragma unroll
      for(int mf=0;mf<4;mf++)
#pragma unroll
        for(int nf=0;nf<4;nf++)
          acc[mf][nf] = mfma16(af[mf], bf[nf], acc[mf][nf]);
    }
  };

  stage(0, 0);
  asm volatile("s_waitcnt vmcnt(0)" ::: "memory");
  __builtin_amdgcn_s_barrier();
  stage(1, 1);
  for(int t = 0; t < NPH; ++t){
    const int bi = t & 1;
    compute(bi);
    bar_lds();
    if(t + 2 < NPH){
      stage(t + 2, bi);
      asm volatile("s_waitcnt vmcnt(8)" ::: "memory");
    } else {
      asm volatile("s_waitcnt vmcnt(0)" ::: "memory");
    }
    __builtin_amdgcn_sched_barrier(0);
    __builtin_amdgcn_s_barrier();
  }

#pragma unroll
  for(int mf=0;mf<4;mf++)
#pragma unroll
    for(int nf=0;nf<4;nf++){
      const int col = n0 + wn*64 + nf*16 + ln;
#pragma unroll
      for(int i=0;i<4;i++){
        const int row = m0 + wm*64 + mf*16 + quad*4 + i;
        unsafeAtomicAdd(outa + (size_t)row*256 + col, acc[mf][nf][i]);
      }
    }
}

// ---------------- BN stats: per-channel sum/sumsq over M=16384 ----------------
__global__ void k_stats(const float* __restrict__ acc, float* __restrict__ sum,
                        float* __restrict__ sq){
  const int m0 = blockIdx.x*64;
  const int c = threadIdx.x;
  float s = 0.f, q = 0.f;
  for(int i=0;i<64;i++){
    float v = acc[(size_t)(m0+i)*256 + c];
    s += v; q += v*v;
  }
  unsafeAtomicAdd(sum + c, s);
  unsafeAtomicAdd(sq + c, q);
}

// ---------------- BN1 + ReLU -> padded bf16 NHWC ----------------
__global__ void k_bn1(const float* __restrict__ acc, const float* __restrict__ sum,
                      const float* __restrict__ sq, const float* __restrict__ g,
                      const float* __restrict__ bt, u16* __restrict__ o){
  __shared__ float sc[256], sh[256];
  const int t = threadIdx.x;
  {
    float mean = sum[t] * (1.f/16384.f);
    float var  = sq[t] * (1.f/16384.f) - mean*mean;
    float rstd = rsqrtf(var + 1e-5f);
    float s = g[t] * rstd;
    sc[t] = s; sh[t] = bt[t] - mean*s;
  }
  __syncthreads();
  const int c4 = (t & 63) * 4;
  const float s0 = sc[c4], s1 = sc[c4+1], s2 = sc[c4+2], s3 = sc[c4+3];
  const float h0 = sh[c4], h1 = sh[c4+1], h2 = sh[c4+2], h3 = sh[c4+3];
#pragma unroll
  for(int k=0;k<4;k++){
    int m = blockIdx.x*16 + k*4 + (t>>6);
    int b = m >> 12, hh = (m >> 6) & 63, ww = m & 63;
    const float4 v = *(const float4*)(acc + (size_t)m*256 + c4);
    unsigned int lo = (unsigned int)(u16)f2bf(fmaxf(0.f, v.x*s0 + h0))
                    | ((unsigned int)(u16)f2bf(fmaxf(0.f, v.y*s1 + h1)) << 16);
    unsigned int hi = (unsigned int)(u16)f2bf(fmaxf(0.f, v.z*s2 + h2))
                    | ((unsigned int)(u16)f2bf(fmaxf(0.f, v.w*s3 + h3)) << 16);
    uint2 pr; pr.x = lo; pr.y = hi;
    *(uint2*)(o + ((size_t)(b*66 + hh+1)*66 + ww+1)*256 + c4) = pr;
  }
}

// ---------------- BN2 + ReLU + NHWC->NCHW fp32 output ----------------
__global__ void k_bn2_out(const float* __restrict__ acc, const float* __restrict__ sum,
                          const float* __restrict__ sq, const float* __restrict__ g,
                          const float* __restrict__ bt, float* __restrict__ out){
  __shared__ float tile[64][65];
  __shared__ float sc[64], sh[64];
  const int t = threadIdx.x;
  const int b = blockIdx.z, c0 = blockIdx.y*64, hw0 = blockIdx.x*64;
  if(t < 64){
    int c = c0 + t;
    float mean = sum[c] * (1.f/16384.f);
    float var  = sq[c] * (1.f/16384.f) - mean*mean;
    float rstd = rsqrtf(var + 1e-5f);
    float s = g[c] * rstd;
    sc[t] = s; sh[t] = bt[c] - mean*s;
  }
  __syncthreads();
#pragma unroll
  for(int k=0;k<16;k++){
    int idx = t + k*256;
    int wl = idx >> 6, cl = idx & 63;
    float v = acc[(size_t)((b<<12) + hw0 + wl)*256 + c0 + cl];
    tile[wl][cl] = fmaxf(0.f, v*sc[cl] + sh[cl]);
  }
  __syncthreads();
#pragma unroll
  for(int k=0;k<16;k++){
    int idx = t + k*256;
    int cl = idx >> 6, wl = idx & 63;
    out[(size_t)(b*256 + c0 + cl)*4096 + hw0 + wl] = tile[wl][cl];
  }
}

extern "C" void kernel_launch(void* const* d_in, const int* in_sizes, int n_in,
                              void* d_out, int out_size, void* d_ws, size_t ws_size,
                              hipStream_t stream){
  const float* in_v  = (const float*)d_in[0];
  const float* in_i  = (const float*)d_in[1];
  const float* w_off = (const float*)d_in[2];
  const float* b_off = (const float*)d_in[3];
  const float* w_dcn = (const float*)d_in[4];
  const float* g1    = (const float*)d_in[5];
  const float* bt1   = (const float*)d_in[6];
  const float* w2    = (const float*)d_in[7];
  const float* g2    = (const float*)d_in[8];
  const float* bt2   = (const float*)d_in[9];
  float* out = (float*)d_out;
  char* ws = (char*)d_ws;

  float* stats     = (float*)(ws + STATS_B);
  float* out2_acc  = (float*)(ws + OUT2_ACC_B);
  u16*   xn_pad    = (u16*)  (ws + XN_PAD_B);
  u16*   out1n_pad = (u16*)  (ws + OUT1N_PAD_B);
  float* out1_acc  = (float*)(ws + OUT1_ACC_B);
  int*   ppix      = (int*)  (ws + PPIX_B);
  float* pwgt      = (float*)(ws + PWGT_B);
  u16*   Ymat      = (u16*)  (ws + Y_B);
  u16*   wall      = (u16*)  (ws + WALL_B);
  u16*   w2t       = (u16*)  (ws + W2T_B);
  float* sum1 = stats,       *sq1 = stats + 256;
  float* sum2 = stats + 512, *sq2 = stats + 768;

  hipMemsetAsync(ws, 0, ZERO_BYTES, stream);
  k_x_to_nhwc<<<dim3(64,8,4), 256, 0, stream>>>(in_v, in_i, xn_pad);
  k_prep_wall<<<5376, 256, 0, stream>>>(w_dcn, w_off, wall);
  k_prep_w2<<<2304, 256, 0, stream>>>(w2, w2t);
  k_gemm_big<<<3024, 256, 0, stream>>>(xn_pad, wall, Ymat);
  k_off_combine<<<256, 256, 0, stream>>>(Ymat, b_off, ppix, pwgt);
  k_combine<<<256, 512, 0, stream>>>(Ymat, ppix, pwgt, out1_acc);
  k_stats<<<256, 256, 0, stream>>>(out1_acc, sum1, sq1);
  k_bn1<<<1024, 256, 0, stream>>>(out1_acc, sum1, sq1, g1, bt1, out1n_pad);
  k_gemm2<<<512, 256, 0, stream>>>(out1n_pad, w2t, out2_acc);
  k_stats<<<256, 256, 0, stream>>>(out2_acc, sum2, sq2);
  k_bn2_out<<<dim3(64,4,4), 256, 0, stream>>>(out2_acc, sum2, sq2, g2, bt2, out);
}

// Round 12
// 350.162 us; speedup vs baseline: 1.2230x; 1.0258x over previous
//
#include <hip/hip_runtime.h>
#include <cstdint>
#include <cstddef>

typedef unsigned short u16;
typedef __attribute__((ext_vector_type(8))) short s16x8;
typedef __attribute__((ext_vector_type(4))) float f32x4;

#define DEV __device__ __forceinline__

DEV float bf2f(short u){
  union { unsigned int i; float f; } v;
  v.i = ((unsigned int)(u16)u) << 16;
  return v.f;
}
DEV short f2bf(float f){
  union { float f; unsigned int i; } v; v.f = f;
  unsigned int u = v.i;
  u += 0x7fffu + ((u >> 16) & 1u);   // RNE
  return (short)(u >> 16);
}
DEV f32x4 f32x4_zero(){
  f32x4 z;
#pragma unroll
  for(int j=0;j<4;j++) z[j]=0.f;
  return z;
}
DEV f32x4 mfma16(s16x8 a, s16x8 b, f32x4 c){
  return __builtin_amdgcn_mfma_f32_16x16x32_bf16(a, b, c, 0, 0, 0);
}
DEV void bar_lds(){
  asm volatile("s_waitcnt lgkmcnt(0)" ::: "memory");
  __builtin_amdgcn_s_barrier();
}
// async global -> LDS, 16 B per lane; per-lane global src, lds dst = base + lane*16
DEV void gload16(const u16* g, u16* l){
  __builtin_amdgcn_global_load_lds(
      (const __attribute__((address_space(1))) unsigned int*)g,
      (__attribute__((address_space(3))) unsigned int*)l, 16, 0, 0);
}

// ---------------- problem constants ----------------
// B=4, Cin=512 (concat), H=W=64, P=9 taps, Cout=256, M = B*H*W = 16384
// Y-formulation: Y[pp, p*256+o] = xn_pad[pp] . W_p  (+ 288 off-conv cols)
// Padded pixel domain: 4*66*66 = 17424 rows, padded to 17536 = 137*128.
// N = 2304 (dcn) + 288 (off, 27 used) -> padded to 2688 = 21*128.
static constexpr size_t STATS_B     = 0;                        // float[1024]
static constexpr size_t OUT2_ACC_B  = 4096;                     // float[16384*256]
static constexpr size_t XN_PAD_B    = 16781312;                 // u16[17536*512]
static constexpr size_t OUT1N_PAD_B = 34738176;                 // u16[4*66*66*256]
static constexpr size_t ZERO_BYTES  = 43659264;
static constexpr size_t OUT1_ACC_B  = 43659264;                 // float[16384*256] (fully written)
static constexpr size_t PPIX_B      = 60436480;                 // int[16384*9*4]
static constexpr size_t PWGT_B      = 62795776;                 // float[16384*9*4]
static constexpr size_t Y_B         = 65155072;                 // u16[17536*2688]
static constexpr size_t WALL_B      = 159428608;                // u16[2688*512]
static constexpr size_t W2T_B       = 162181120;                // u16[256*2304]
// end ~163.4 MB

// ---------------- NCHW fp32 (concat) -> padded NHWC bf16 ----------------
__global__ void k_x_to_nhwc(const float* __restrict__ v, const float* __restrict__ vi,
                            u16* __restrict__ xn){
  __shared__ float tile[64][65];
  const int b = blockIdx.z, c0 = blockIdx.y*64, hw0 = blockIdx.x*64;
  const int h = hw0 >> 6;
  const float* src = (c0 < 256) ? (v  + ((size_t)b*256 + c0)      *4096)
                                : (vi + ((size_t)b*256 + (c0-256))*4096);
  const int t = threadIdx.x;
#pragma unroll
  for(int k=0;k<16;k++){
    int idx = t + k*256;
    int cl = idx >> 6, wl = idx & 63;
    tile[cl][wl] = src[(size_t)cl*4096 + hw0 + wl];
  }
  __syncthreads();
#pragma unroll
  for(int k=0;k<16;k++){
    int idx = t + k*256;
    int wl = idx >> 6, cl = idx & 63;
    xn[((size_t)(b*66 + h+1)*66 + wl+1)*512 + c0 + cl] = (u16)f2bf(tile[cl][wl]);
  }
}

// ---------------- combined weight repack: [2688][512] bf16 ----------------
__global__ void k_prep_wall(const float* __restrict__ wdcn, const float* __restrict__ woff,
                            u16* __restrict__ wt){
  int idx = blockIdx.x*256 + threadIdx.x;
  if(idx >= 2688*512) return;
  int n = idx >> 9, c = idx & 511;
  float val = 0.f;
  if(n < 2304){
    int p = n >> 8, o = n & 255;
    val = wdcn[(size_t)(o*512 + c)*9 + p];
  } else if(n < 2592){
    int q = n - 2304, p = q >> 5, nn = q & 31;
    if(nn < 27) val = woff[(size_t)(nn*512 + c)*9 + p];
  }
  wt[idx] = (u16)f2bf(val);
}
__global__ void k_prep_w2(const float* __restrict__ w, u16* __restrict__ wt){
  int idx = blockIdx.x*256 + threadIdx.x;
  if(idx >= 256*2304) return;
  int n = idx / 2304, k = idx % 2304;
  int t = k >> 8, c = k & 255;
  wt[idx] = (u16)f2bf(w[(size_t)(n*256 + c)*9 + t]);
}

// ---------------- dense GEMM: Y[17536][2688] = xn_pad[17536][512] x Wall^T ----------------
// 128x128 tile, BK=64, dbuf LDS, counted vmcnt(8). 3 n-tiles per block chained
// through ONE hot pipeline (24 phases; pass boundary = flush acc->Y + vmcnt(0)).
// XCD-aware: xcd owns mt = xcd (mod 8); (mt-group, n-group) iterate within.
// Linear grid 8*18*7 = 1008; ~5% no-op (mt>=137).
__global__ __launch_bounds__(256, 2) void k_gemm_big(
    const u16* __restrict__ A, const u16* __restrict__ wt, u16* __restrict__ Y){
  const int bid = blockIdx.x;
  const int xcd = bid & 7;
  const int j   = bid >> 3;               // 0..125
  const int mt  = xcd + 8*(j/7);
  const int ng  = j % 7;                  // n-group: tiles ng*3 .. ng*3+2
  if(mt >= 137) return;
  __shared__ short A_lds[2][8][128][8];   // 32 KB
  __shared__ short B_lds[2][8][128][8];   // 32 KB
  const int tid = threadIdx.x;
  const int lane = tid & 63, wid = tid >> 6;
  const int quad = lane >> 4, ln = lane & 15;
  const int wm = wid >> 1, wn = wid & 1;
  const int m0 = mt * 128;
  constexpr int NPH = 24;                 // 3 passes x 8 K-steps
  f32x4 acc[4][4];
#pragma unroll
  for(int mf=0;mf<4;mf++)
#pragma unroll
    for(int nf=0;nf<4;nf++) acc[mf][nf] = f32x4_zero();

  auto stage = [&](int p, int bi){        // 8 gload16 per wave (4 A + 4 B)
    const int n0 = (ng*3 + (p >> 3)) * 128;
    const int k0 = (p & 7) * 64;
#pragma unroll
    for(int i=0;i<4;i++){
      const int idx = wid*4 + i;          // 0..15
      const int s = idx >> 1, rh = (idx & 1)*64;
      gload16(A  + (size_t)(m0 + rh + lane)*512 + k0 + s*8, (u16*)&A_lds[bi][s][rh][0]);
      gload16(wt + (size_t)(n0 + rh + lane)*512 + k0 + s*8, (u16*)&B_lds[bi][s][rh][0]);
    }
  };
  auto compute = [&](int bi){             // 32 MFMA per wave
#pragma unroll
    for(int kk=0;kk<2;kk++){
      s16x8 af[4], bf[4];
#pragma unroll
      for(int mf=0;mf<4;mf++)
        af[mf] = *(const s16x8*)&A_lds[bi][kk*4+quad][wm*64 + mf*16 + ln][0];
#pragma unroll
      for(int nf=0;nf<4;nf++)
        bf[nf] = *(const s16x8*)&B_lds[bi][kk*4+quad][wn*64 + nf*16 + ln][0];
#pragma unroll
      for(int mf=0;mf<4;mf++)
#pragma unroll
        for(int nf=0;nf<4;nf++)
          acc[mf][nf] = mfma16(af[mf], bf[nf], acc[mf][nf]);
    }
  };
  auto flushY = [&](int pass){            // write pass's 128x128 tile, reset acc
    const int n0 = (ng*3 + pass) * 128;
#pragma unroll
    for(int mf=0;mf<4;mf++)
#pragma unroll
      for(int nf=0;nf<4;nf++){
        const int col = n0 + wn*64 + nf*16 + ln;
#pragma unroll
        for(int i=0;i<4;i++){
          const int row = m0 + wm*64 + mf*16 + quad*4 + i;
          Y[(size_t)row*2688 + col] = (u16)f2bf(acc[mf][nf][i]);
        }
        acc[mf][nf] = f32x4_zero();
      }
  };

  stage(0, 0);
  asm volatile("s_waitcnt vmcnt(0)" ::: "memory");
  __builtin_amdgcn_s_barrier();
  stage(1, 1);
  for(int p = 0; p < NPH; ++p){
    const int bi = p & 1;
    compute(bi);
    bar_lds();
    const bool boundary = (p & 7) == 7;
    if(boundary) flushY(p >> 3);          // Y-stores issued before the drain below
    if(p + 2 < NPH) stage(p + 2, bi);
    if(boundary || p + 2 >= NPH){
      asm volatile("s_waitcnt vmcnt(0)" ::: "memory");   // drain stores+loads (3x/block)
    } else {
      asm volatile("s_waitcnt vmcnt(8)" ::: "memory");   // stage(p+1) landed
    }
    __builtin_amdgcn_sched_barrier(0);
    __builtin_amdgcn_s_barrier();
  }
}

// ---------------- off-combine: 9-tap shifted sum of Y off-cols -> bilinear tables -------
__global__ __launch_bounds__(256) void k_off_combine(
    const u16* __restrict__ Y, const float* __restrict__ boff,
    int* __restrict__ ppix, float* __restrict__ pwgt){
  __shared__ float offs[64][32];
  const int t = threadIdx.x;
  const int b = blockIdx.x >> 6, h = blockIdx.x & 63;
  const int w = t >> 2, g = t & 3;
  float acc[8];
#pragma unroll
  for(int j=0;j<8;j++) acc[j] = 0.f;
  for(int p=0;p<9;p++){
    const int pp = (b*66 + h + p/3)*66 + (w + p%3);   // fixed 3x3 taps, padded coords
    s16x8 v = *(const s16x8*)(Y + (size_t)pp*2688 + 2304 + p*32 + g*8);
#pragma unroll
    for(int j=0;j<8;j++) acc[j] += bf2f(v[j]);
  }
#pragma unroll
  for(int j=0;j<8;j++) offs[w][g*8 + j] = acc[j];
  __syncthreads();
  for(int id = t; id < 576; id += 256){
    const int tp = id / 64, ww = id & 63;
    const int m = (b<<12) + (h<<6) + ww;
    float dy = offs[ww][2*tp]   + boff[2*tp];
    float dx = offs[ww][2*tp+1] + boff[2*tp+1];
    float mz = offs[ww][18+tp]  + boff[18+tp];
    float mk = 1.f / (1.f + expf(-mz));
    float ypos = (float)(h - 1 + tp/3) + dy;
    float xpos = (float)(ww - 1 + tp%3) + dx;
    float y0f = floorf(ypos), x0f = floorf(xpos);
    float ly = ypos - y0f, lx = xpos - x0f;
    int y0 = (int)y0f, x0 = (int)x0f;
    const int id4 = (m*9 + tp)*4;
#pragma unroll
    for(int k=0;k<4;k++){
      int ddy = k >> 1, ddx = k & 1;
      int yi = y0 + ddy, xi = x0 + ddx;
      // clamp into padded domain; border rows of Y are exact zeros
      int yc = yi < -1 ? -1 : (yi > 64 ? 64 : yi);
      int xc = xi < -1 ? -1 : (xi > 64 ? 64 : xi);
      float wk = (ddy ? ly : 1.f-ly) * (ddx ? lx : 1.f-lx) * mk;
      ppix[id4+k] = (b*66 + yc+1)*66 + xc+1;          // padded pixel index
      pwgt[id4+k] = wk;
    }
  }
}

// ---------------- bilinear combine + fused BN1 stats ----------------
// grid 256 (one (b,h) row), 512 threads = 8 waves x 8 pixels; lane owns 4 cols.
// Block owns full 64 rows x 256 cols of out1 -> per-column sum/sumsq reduced in
// LDS and atomically added once per column per block (deletes the k_stats1 pass).
__global__ __launch_bounds__(512) void k_combine(
    const u16* __restrict__ Y, const int* __restrict__ ppix,
    const float* __restrict__ pwgt, float* __restrict__ out1,
    float* __restrict__ sum1, float* __restrict__ sq1){
  __shared__ int   s_pp[64][9][4];
  __shared__ float s_wg[64][9][4];
  __shared__ float s_red[2][8][256];
  const int t = threadIdx.x;
  const int b = blockIdx.x >> 6, h = blockIdx.x & 63;
  const int m_row = (b<<12) + (h<<6);
  for(int id = t; id < 576; id += 512){
    const int mo = id / 9, tp = id - mo*9;
    const size_t i4 = ((size_t)(m_row + mo)*9 + tp)*4;
    int4   pp4 = *(const int4*)  (ppix + i4);
    float4 wg4 = *(const float4*)(pwgt + i4);
    s_pp[mo][tp][0] = pp4.x; s_pp[mo][tp][1] = pp4.y;
    s_pp[mo][tp][2] = pp4.z; s_pp[mo][tp][3] = pp4.w;
    s_wg[mo][tp][0] = wg4.x; s_wg[mo][tp][1] = wg4.y;
    s_wg[mo][tp][2] = wg4.z; s_wg[mo][tp][3] = wg4.w;
  }
  __syncthreads();
  const int wv = t >> 6, lane = t & 63;
  const int c0 = lane*4;
  const int pw0 = wv*8;
  float acc[8][4];
#pragma unroll
  for(int pw=0;pw<8;pw++)
#pragma unroll
    for(int j=0;j<4;j++) acc[pw][j] = 0.f;

  for(int tp = 0; tp < 9; ++tp){
    const int cb = tp*256 + c0;
#pragma unroll
    for(int pw=0;pw<8;pw++){
      const int px = pw0 + pw;
#pragma unroll
      for(int k=0;k<4;k++){
        const float wk = s_wg[px][tp][k];
        const int   pp = s_pp[px][tp][k];
        ushort4 v = *(const ushort4*)(Y + (size_t)pp*2688 + cb);
        acc[pw][0] = fmaf(wk, bf2f((short)v.x), acc[pw][0]);
        acc[pw][1] = fmaf(wk, bf2f((short)v.y), acc[pw][1]);
        acc[pw][2] = fmaf(wk, bf2f((short)v.z), acc[pw][2]);
        acc[pw][3] = fmaf(wk, bf2f((short)v.w), acc[pw][3]);
      }
    }
  }
  float ls[4] = {0.f,0.f,0.f,0.f}, lq[4] = {0.f,0.f,0.f,0.f};
#pragma unroll
  for(int pw=0;pw<8;pw++){
    float4 o4;
    o4.x = acc[pw][0]; o4.y = acc[pw][1]; o4.z = acc[pw][2]; o4.w = acc[pw][3];
    *(float4*)(out1 + (size_t)(m_row + pw0 + pw)*256 + c0) = o4;
#pragma unroll
    for(int j=0;j<4;j++){
      ls[j] += acc[pw][j];
      lq[j] = fmaf(acc[pw][j], acc[pw][j], lq[j]);
    }
  }
#pragma unroll
  for(int j=0;j<4;j++){
    s_red[0][wv][c0+j] = ls[j];
    s_red[1][wv][c0+j] = lq[j];
  }
  __syncthreads();
  if(t < 256){
    float S = 0.f, Q = 0.f;
#pragma unroll
    for(int w8=0;w8<8;w8++){ S += s_red[0][w8][t]; Q += s_red[1][w8][t]; }
    unsafeAtomicAdd(sum1 + t, S);
    unsafeAtomicAdd(sq1 + t, Q);
  }
}

// ---------------- GEMM2: out2 = im2col(out1n_pad)[16384][2304] x W2T[256][2304]^T ------
// XCD-aware: linear grid 512; each XCD owns m-tiles {xcd, xcd+8, ...}.
__global__ __launch_bounds__(256, 2) void k_gemm2(
    const u16* __restrict__ a_pad, const u16* __restrict__ wt, float* __restrict__ outa){
  const int bid = blockIdx.x;
  const int xcd = bid & 7;
  const int j   = bid >> 3;               // 0..63
  const int mt  = xcd + 8*(j >> 2);       // 0..127
  const int rest = j & 3;
  const int nt  = rest & 1;
  const int kz  = rest >> 1;
  __shared__ short A_lds[2][8][128][8];   // 32 KB
  __shared__ short B_lds[2][8][128][8];   // 32 KB
  const int tid = threadIdx.x;
  const int lane = tid & 63, wid = tid >> 6;
  const int quad = lane >> 4, ln = lane & 15;
  const int wm = wid >> 1, wn = wid & 1;
  const int m0 = mt * 128;
  const int n0 = nt * 128;
  const int kbase = kz * 1152;
  const int b = m0 >> 12;
  const int h0 = (m0 & 4095) >> 6;
  constexpr int NPH = 18;
  f32x4 acc[4][4];
#pragma unroll
  for(int mf=0;mf<4;mf++)
#pragma unroll
    for(int nf=0;nf<4;nf++) acc[mf][nf] = f32x4_zero();

  auto stage = [&](int t, int bi){
    const int k0 = kbase + t*64;
    const int tp = k0 >> 8, cit = k0 & 255;
    const int ty = tp/3, tx = tp - ty*3;
#pragma unroll
    for(int i=0;i<4;i++){
      const int idx = wid*4 + i;
      const int s = idx >> 1, rh = (idx & 1)*64;
      const int hh = h0 + (rh >> 6) + ty;
      gload16(a_pad + ((size_t)(b*66 + hh)*66 + lane + tx)*256 + cit + s*8,
              (u16*)&A_lds[bi][s][rh][0]);
      gload16(wt + (size_t)(n0 + rh + lane)*2304 + k0 + s*8,
              (u16*)&B_lds[bi][s][rh][0]);
    }
  };
  auto compute = [&](int bi){
#pragma unroll
    for(int kk=0;kk<2;kk++){
      s16x8 af[4], bf[4];
#pragma unroll
      for(int mf=0;mf<4;mf++)
        af[mf] = *(const s16x8*)&A_lds[bi][kk*4+quad][wm*64 + mf*16 + ln][0];
#pragma unroll
      for(int nf=0;nf<4;nf++)
        bf[nf] = *(const s16x8*)&B_lds[bi][kk*4+quad][wn*64 + nf*16 + ln][0];
#pragma unroll
      for(int mf=0;mf<4;mf++)
#pragma unroll
        for(int nf=0;nf<4;nf++)
          acc[mf][nf] = mfma16(af[mf], bf[nf], acc[mf][nf]);
    }
  };

  stage(0, 0);
  asm volatile("s_waitcnt vmcnt(0)" ::: "memory");
  __builtin_amdgcn_s_barrier();
  stage(1, 1);
  for(int t = 0; t < NPH; ++t){
    const int bi = t & 1;
    compute(bi);
    bar_lds();
    if(t + 2 < NPH){
      stage(t + 2, bi);
      asm volatile("s_waitcnt vmcnt(8)" ::: "memory");
    } else {
      asm volatile("s_waitcnt vmcnt(0)" ::: "memory");
    }
    __builtin_amdgcn_sched_barrier(0);
    __builtin_amdgcn_s_barrier();
  }

#pragma unroll
  for(int mf=0;mf<4;mf++)
#pragma unroll
    for(int nf=0;nf<4;nf++){
      const int col = n0 + wn*64 + nf*16 + ln;
#pragma unroll
      for(int i=0;i<4;i++){
        const int row = m0 + wm*64 + mf*16 + quad*4 + i;
        unsafeAtomicAdd(outa + (size_t)row*256 + col, acc[mf][nf][i]);
      }
    }
}

// ---------------- BN stats: per-channel sum/sumsq over M=16384 ----------------
__global__ void k_stats(const float* __restrict__ acc, float* __restrict__ sum,
                        float* __restrict__ sq){
  const int m0 = blockIdx.x*64;
  const int c = threadIdx.x;
  float s = 0.f, q = 0.f;
  for(int i=0;i<64;i++){
    float v = acc[(size_t)(m0+i)*256 + c];
    s += v; q += v*v;
  }
  unsafeAtomicAdd(sum + c, s);
  unsafeAtomicAdd(sq + c, q);
}

// ---------------- BN1 + ReLU -> padded bf16 NHWC ----------------
__global__ void k_bn1(const float* __restrict__ acc, const float* __restrict__ sum,
                      const float* __restrict__ sq, const float* __restrict__ g,
                      const float* __restrict__ bt, u16* __restrict__ o){
  __shared__ float sc[256], sh[256];
  const int t = threadIdx.x;
  {
    float mean = sum[t] * (1.f/16384.f);
    float var  = sq[t] * (1.f/16384.f) - mean*mean;
    float rstd = rsqrtf(var + 1e-5f);
    float s = g[t] * rstd;
    sc[t] = s; sh[t] = bt[t] - mean*s;
  }
  __syncthreads();
  const int c4 = (t & 63) * 4;
  const float s0 = sc[c4], s1 = sc[c4+1], s2 = sc[c4+2], s3 = sc[c4+3];
  const float h0 = sh[c4], h1 = sh[c4+1], h2 = sh[c4+2], h3 = sh[c4+3];
#pragma unroll
  for(int k=0;k<4;k++){
    int m = blockIdx.x*16 + k*4 + (t>>6);
    int b = m >> 12, hh = (m >> 6) & 63, ww = m & 63;
    const float4 v = *(const float4*)(acc + (size_t)m*256 + c4);
    unsigned int lo = (unsigned int)(u16)f2bf(fmaxf(0.f, v.x*s0 + h0))
                    | ((unsigned int)(u16)f2bf(fmaxf(0.f, v.y*s1 + h1)) << 16);
    unsigned int hi = (unsigned int)(u16)f2bf(fmaxf(0.f, v.z*s2 + h2))
                    | ((unsigned int)(u16)f2bf(fmaxf(0.f, v.w*s3 + h3)) << 16);
    uint2 pr; pr.x = lo; pr.y = hi;
    *(uint2*)(o + ((size_t)(b*66 + hh+1)*66 + ww+1)*256 + c4) = pr;
  }
}

// ---------------- BN2 + ReLU + NHWC->NCHW fp32 output ----------------
__global__ void k_bn2_out(const float* __restrict__ acc, const float* __restrict__ sum,
                          const float* __restrict__ sq, const float* __restrict__ g,
                          const float* __restrict__ bt, float* __restrict__ out){
  __shared__ float tile[64][65];
  __shared__ float sc[64], sh[64];
  const int t = threadIdx.x;
  const int b = blockIdx.z, c0 = blockIdx.y*64, hw0 = blockIdx.x*64;
  if(t < 64){
    int c = c0 + t;
    float mean = sum[c] * (1.f/16384.f);
    float var  = sq[c] * (1.f/16384.f) - mean*mean;
    float rstd = rsqrtf(var + 1e-5f);
    float s = g[c] * rstd;
    sc[t] = s; sh[t] = bt[c] - mean*s;
  }
  __syncthreads();
#pragma unroll
  for(int k=0;k<16;k++){
    int idx = t + k*256;
    int wl = idx >> 6, cl = idx & 63;
    float v = acc[(size_t)((b<<12) + hw0 + wl)*256 + c0 + cl];
    tile[wl][cl] = fmaxf(0.f, v*sc[cl] + sh[cl]);
  }
  __syncthreads();
#pragma unroll
  for(int k=0;k<16;k++){
    int idx = t + k*256;
    int cl = idx >> 6, wl = idx & 63;
    out[(size_t)(b*256 + c0 + cl)*4096 + hw0 + wl] = tile[wl][cl];
  }
}

extern "C" void kernel_launch(void* const* d_in, const int* in_sizes, int n_in,
                              void* d_out, int out_size, void* d_ws, size_t ws_size,
                              hipStream_t stream){
  const float* in_v  = (const float*)d_in[0];
  const float* in_i  = (const float*)d_in[1];
  const float* w_off = (const float*)d_in[2];
  const float* b_off = (const float*)d_in[3];
  const float* w_dcn = (const float*)d_in[4];
  const float* g1    = (const float*)d_in[5];
  const float* bt1   = (const float*)d_in[6];
  const float* w2    = (const float*)d_in[7];
  const float* g2    = (const float*)d_in[8];
  const float* bt2   = (const float*)d_in[9];
  float* out = (float*)d_out;
  char* ws = (char*)d_ws;

  float* stats     = (float*)(ws + STATS_B);
  float* out2_acc  = (float*)(ws + OUT2_ACC_B);
  u16*   xn_pad    = (u16*)  (ws + XN_PAD_B);
  u16*   out1n_pad = (u16*)  (ws + OUT1N_PAD_B);
  float* out1_acc  = (float*)(ws + OUT1_ACC_B);
  int*   ppix      = (int*)  (ws + PPIX_B);
  float* pwgt      = (float*)(ws + PWGT_B);
  u16*   Ymat      = (u16*)  (ws + Y_B);
  u16*   wall      = (u16*)  (ws + WALL_B);
  u16*   w2t       = (u16*)  (ws + W2T_B);
  float* sum1 = stats,       *sq1 = stats + 256;
  float* sum2 = stats + 512, *sq2 = stats + 768;

  hipMemsetAsync(ws, 0, ZERO_BYTES, stream);
  k_x_to_nhwc<<<dim3(64,8,4), 256, 0, stream>>>(in_v, in_i, xn_pad);
  k_prep_wall<<<5376, 256, 0, stream>>>(w_dcn, w_off, wall);
  k_prep_w2<<<2304, 256, 0, stream>>>(w2, w2t);
  k_gemm_big<<<1008, 256, 0, stream>>>(xn_pad, wall, Ymat);
  k_off_combine<<<256, 256, 0, stream>>>(Ymat, b_off, ppix, pwgt);
  k_combine<<<256, 512, 0, stream>>>(Ymat, ppix, pwgt, out1_acc, sum1, sq1);
  k_bn1<<<1024, 256, 0, stream>>>(out1_acc, sum1, sq1, g1, bt1, out1n_pad);
  k_gemm2<<<512, 256, 0, stream>>>(out1n_pad, w2t, out2_acc);
  k_stats<<<256, 256, 0, stream>>>(out2_acc, sum2, sq2);
  k_bn2_out<<<dim3(64,4,4), 256, 0, stream>>>(out2_acc, sum2, sq2, g2, bt2, out);
}